// Round 7
// baseline (261.670 us; speedup 1.0000x reference)
//
#include <hip/hip_runtime.h>
#include <math.h>

#define PI_D 3.14159265358979323846

typedef short v8s __attribute__((ext_vector_type(8)));
typedef float v4f __attribute__((ext_vector_type(4)));

// ---------------- workspace layout (float offsets), total 27791872 floats = 111.2 MB ----------------
constexpr size_t OFF_PA   = 0;                   // legfwd A-frags bf16: per m, A[l][t]  (256 slices, 32 MB)
constexpr size_t OFF_PT   = 8388608;             // leginv A-frags bf16: per m, A[t][l]  (128 slices, 16 MB)
constexpr size_t OFF_SFRE = 12582912;            // flm re [m][l][c] fp32 (8 MB)
constexpr size_t OFF_SFIM = 14680064;            // flm im
constexpr size_t OFF_BF   = 16777216;            // fwd-DFT B-frags bf16 [t][ks16][nt2][lane][8] (8 MB)
constexpr size_t OFF_BF2  = 18874368;            // legfwd B-frags bf16 [m][ks8][nt4][lane][8] (8 MB)
constexpr size_t OFF_BI   = 20971520;            // inv-DFT B-frags bf16 [t][ks16][nt2][lane][8] (8 MB)
constexpr size_t OFF_AF   = 23068672;            // fwd DFT A-frags bf16 (512 KB)
constexpr size_t OFF_AI   = 23199744;            // inv DFT A-frags bf16 (512 KB)
constexpr size_t OFF_WPR  = 23330816;            // premult conv w [l][o][i] fp32
constexpr size_t OFF_WPI  = 23461888;
constexpr size_t OFF_WQ   = 23592960;            // 256 quadrature weights
constexpr size_t OFF_TC   = 23593216;            // 256 (t_cplx re|im)
constexpr size_t OFF_WLW  = 23593472;            // 128*4 l-resize weights
constexpr size_t OFF_WLI  = 23593984;            // 128*4 l-resize indices (int)
constexpr size_t OFF_WMW  = 23594496;            // 255*6 m-resize weights
constexpr size_t OFF_WMI  = 23596032;            // 255*6 m-resize indices (int)
constexpr size_t OFF_FRE  = 23597568;            // fwd-DFT out fp32 F[m][t][c] (8 MB)
constexpr size_t OFF_FIM  = 25694720;            // (8 MB); end = 27791872 floats
// overlays (lifetimes disjoint):
constexpr size_t OFF_CRE  = OFF_BF;              // conv out fp32 [j][l][c] (BF dead after gemm_f)
constexpr size_t OFF_CIM  = OFF_BF + 1044480;
constexpr size_t OFF_RRE  = OFF_BF2;             // resized flm fp32 [j'][l'][c] (BF2 dead after legfwd)
constexpr size_t OFF_RIM  = OFF_BF2 + 1044480;
constexpr size_t OFF_BI2  = OFF_FRE;             // leginv B-frags bf16 [j][ks4][nt4][lane][8] (FRE dead after repack_bf2)
constexpr size_t OFF_GRE  = OFF_SFRE;            // G fp32 [t][j][c] (SFRE dead after resize)
constexpr size_t OFF_GIM  = OFF_SFIM;

__device__ __forceinline__ float4 ld4(const float* p) { return *(const float4*)p; }

__device__ __forceinline__ short f2bf(float f) {   // RTNE float->bf16 bits
  unsigned u = __float_as_uint(f);
  unsigned r = (u + 0x7FFFu + ((u >> 16) & 1u)) >> 16;
  return (short)r;
}

// ---------------- setup: quadrature, t_cplx, resize taps ----------------
__global__ void k_setup_small(const float* t_emb, const float* w_tr, const float* b_tr,
                              const float* w_ti, const float* b_ti, float* ws) {
  int tid = threadIdx.x;
  if (tid < 256) {
    double theta = PI_D * (2.0 * tid + 1.0) / 511.0;
    double dang = 2.0 * PI_D / 511.0;
    ws[OFF_WQ + tid] = (float)(sin(theta) * dang * dang);
  }
  {
    int h = tid >> 7, o = tid & 127;
    const float* W = h ? w_ti : w_tr;
    float s = h ? b_ti[o] : b_tr[o];
    for (int T = 0; T < 256; ++T) s += t_emb[T] * W[T * 128 + o];
    ws[OFF_TC + h * 128 + o] = s;
  }
  if (tid < 128) {
    double sf = 2.0 * tid + 0.5;
    double wv[4]; int iv[4]; double wsum = 0.0;
    for (int a = 0; a < 4; ++a) {
      int t = 2 * tid - 1 + a;
      double r = 1.0 - fabs(sf - (double)t) * 0.5;
      bool valid = (t >= 0 && t < 256 && r > 0.0);
      wv[a] = valid ? r : 0.0; iv[a] = valid ? t : 0;
      wsum += wv[a];
    }
    for (int a = 0; a < 4; ++a) {
      ws[OFF_WLW + tid * 4 + a] = (float)(wv[a] / wsum);
      ((int*)(ws + OFF_WLI))[tid * 4 + a] = iv[a];
    }
  }
  if (tid < 255) {
    double inv = 511.0 / 255.0;
    double sf = (tid + 0.5) * inv - 0.5;
    int t0 = (int)floor(sf) - 2;
    double wv[6]; int iv[6]; double wsum = 0.0;
    for (int b = 0; b < 6; ++b) {
      int t = t0 + b;
      double r = 1.0 - fabs(sf - (double)t) * (255.0 / 511.0);
      bool valid = (t >= 0 && t < 511 && r > 0.0);
      wv[b] = valid ? r : 0.0; iv[b] = valid ? t : 0;
      wsum += wv[b];
    }
    for (int b = 0; b < 6; ++b) {
      ws[OFF_WMW + tid * 6 + b] = (float)(wv[b] / wsum);
      ((int*)(ws + OFF_WMI))[tid * 6 + b] = iv[b];
    }
  }
}

// ---------------- premultiplied conv weights, transposed [l][o][i] ----------------
__global__ void k_wprep(const float* wr_, const float* wi_, float* ws) { // grid 512 x 256
  int gid = blockIdx.x * 256 + threadIdx.x;
  int l = gid >> 10, rem = gid & 1023, o = rem >> 5, i = rem & 31;
  float wr = wr_[(l << 10) + i * 32 + o];
  float wi = wi_[(l << 10) + i * 32 + o];
  float tcr = ws[OFF_TC + l], tci = ws[OFF_TC + 128 + l];
  ws[OFF_WPR + gid] = tcr * wr - tci * wi;
  ws[OFF_WPI + gid] = tcr * wi + tci * wr;
}

// ---------------- Legendre basis -> bf16 MFMA A-frag tables (LDS-staged, coalesced) ----------------
__global__ __launch_bounds__(256) void k_legendre(float* ws) {   // grid 256 (m) x 256 (t)
  int m = blockIdx.x, t = threadIdx.x;
  __shared__ double cA[256], cB[256], cS[256];
  {
    int l = t;
    if (l >= 1) cS[l] = -sqrt((2.0 * l + 1.0) / (2.0 * l));
    if (l >= m + 2) {
      double ll = l, mm = m;
      double den = ll * ll - mm * mm;
      cA[l] = sqrt((4.0 * ll * ll - 1.0) / den);
      cB[l] = sqrt((2.0 * ll + 1.0) * (ll - 1.0 - mm) * (ll - 1.0 + mm) /
                   ((2.0 * ll - 3.0) * den));
    }
  }
  __syncthreads();
  __shared__ short tile[16 * 280];
  __shared__ short tileT[256 * 34];
  bool wantPT = (m < 128);
  short* PAp = (short*)(ws + OFF_PA) + (size_t)m * 65536;
  short* PTp = (short*)(ws + OFF_PT) + (size_t)m * 65536;
  double theta = PI_D * (2.0 * t + 1.0) / 511.0;
  double ct = cos(theta), st = sin(theta);
  double p0 = sqrt(1.0 / (4.0 * PI_D));
  for (int k = 1; k <= m; ++k) p0 *= cS[k] * st;
  double pm1 = 0.0, pcur = 0.0;
  for (int lt = 0; lt < 16; ++lt) {
    for (int li = 0; li < 16; ++li) {
      int l = lt * 16 + li;
      float v;
      if (l < m) v = 0.f;
      else if (l == m) { pcur = p0; v = (float)pcur; }
      else if (l == m + 1) { pm1 = pcur; pcur = sqrt(2.0 * m + 3.0) * ct * pm1; v = (float)pcur; }
      else { double p2 = cA[l] * ct * pcur - cB[l] * pm1; pm1 = pcur; pcur = p2; v = (float)p2; }
      short bv = f2bf(v);
      tile[li * 280 + t] = bv;
      if (wantPT) tileT[t * 34 + li] = bv;
    }
    __syncthreads();
#pragma unroll
    for (int pass = 0; pass < 2; ++pass) {
      int ch = pass * 256 + t;
      int li = ch & 15, T0 = ch >> 4;
      size_t dst = (size_t)lt * 4096 + (size_t)(T0 >> 2) * 512 + (size_t)((T0 & 3) * 16 + li) * 8;
      *(v8s*)(PAp + dst) = *(const v8s*)(tile + li * 280 + T0 * 8);
    }
    if (wantPT) {
#pragma unroll
      for (int pass = 0; pass < 2; ++pass) {
        int ch = pass * 256 + t;
        int tt = ch >> 1, li0 = (ch & 1) * 8;
        size_t dst = (size_t)(tt >> 4) * 4096 + (size_t)(lt >> 1) * 512 +
                     (size_t)(((lt & 1) * 2 + (li0 >> 3)) * 16 + (tt & 15)) * 8;
        const int* src = (const int*)(tileT + tt * 34 + li0);
        int* d = (int*)(PTp + dst);
        d[0] = src[0]; d[1] = src[1]; d[2] = src[2]; d[3] = src[3];
      }
    }
    __syncthreads();
  }
}

// ---------------- DFT A-fragment tables (bf16, MFMA A-operand layout), fused ----------------
__global__ void k_atab(float* ws) { // grid 2048 x 256
  int g = blockIdx.x * 256 + threadIdx.x;
  if (g < 262144) {
    int gid = g;
    int j = gid & 7, lane = (gid >> 3) & 63, ks = (gid >> 9) & 15, mt = gid >> 13;
    int m = mt * 16 + (lane & 15);
    int k = ks * 32 + ((lane >> 4) << 3) + j;
    float v = 0.f;
    if (k < 511) {
      int mm = (m < 256) ? m : m - 256;
      int kk = (mm * k) % 511;
      double ang = (2.0 * PI_D / 511.0) * (double)kk;
      v = (m < 256) ? (float)cos(ang) : -(float)sin(ang);
    }
    ((short*)(ws + OFF_AF))[gid] = f2bf(v);
  } else {
    int gid = g - 262144;
    int j = gid & 7, lane = (gid >> 3) & 63, ks = (gid >> 9) & 15, mt = gid >> 13;
    int m = mt * 16 + (lane & 15);
    int k = ks * 32 + ((lane >> 4) << 3) + j;
    float v = 0.f;
    if (m < 511 && k < 510) {
      int jj = (k < 255) ? k : k - 255;
      int jm = jj - 127;
      int kk = ((jm * m) % 511 + 511) % 511;
      double ang = (2.0 * PI_D / 511.0) * (double)kk;
      v = (k < 255) ? (float)cos(ang) : -(float)sin(ang);
    }
    ((short*)(ws + OFF_AI))[gid] = f2bf(v);
  }
}

// ---------------- fwd-DFT B-fragment repack (wq folded) ----------------
__global__ void k_bfrag_f(const float* x, float* ws) { // grid 2048 x 256
  int gid = blockIdx.x * 256 + threadIdx.x;
  int lane = gid & 63, nt = (gid >> 6) & 1, ks = (gid >> 7) & 15, t = gid >> 11;
  int c = nt * 16 + (lane & 15);
  int phiB = ks * 32 + ((lane >> 4) << 3);
  float wq = ws[OFF_WQ + t];
  v8s tmp;
#pragma unroll
  for (int j = 0; j < 8; ++j) {
    int phi = phiB + j;
    tmp[j] = (phi < 511) ? f2bf(wq * x[((size_t)t * 511 + phi) * 32 + c]) : (short)0;
  }
  ((v8s*)(ws + OFF_BF))[gid] = tmp;
}

// ---------------- fwd DFT MFMA GEMM -> fp32 F[m][t][c] (coalesced epilogue) ----------------
__global__ __launch_bounds__(256) void k_gemm_f(float* ws) { // grid (2, 256)
  int nt = blockIdx.x, t = blockIdx.y;
  int tid = threadIdx.x, wave = tid >> 6, lane = tid & 63;
  const v8s* A = (const v8s*)(ws + OFF_AF);
  const v8s* B = (const v8s*)(ws + OFF_BF);
  int mtB = wave * 8;
  v4f acc[8];
#pragma unroll
  for (int i = 0; i < 8; ++i) acc[i] = (v4f){0.f, 0.f, 0.f, 0.f};
  for (int ks = 0; ks < 16; ++ks) {
    v8s b = B[(size_t)((t * 16 + ks) * 2 + nt) * 64 + lane];
#pragma unroll
    for (int i = 0; i < 8; ++i) {
      v8s a = A[(size_t)((mtB + i) * 16 + ks) * 64 + lane];
      acc[i] = __builtin_amdgcn_mfma_f32_16x16x32_bf16(a, b, acc[i], 0, 0, 0);
    }
  }
  int quad = lane >> 4, cn = nt * 16 + (lane & 15);
#pragma unroll
  for (int i = 0; i < 8; ++i) {
    int mt = mtB + i;
#pragma unroll
    for (int r = 0; r < 4; ++r) {
      int mp = mt * 16 + quad * 4 + r;
      float v = acc[i][r];
      if (mp < 256) ws[OFF_FRE + ((size_t)mp * 256 + t) * 32 + cn] = v;
      else          ws[OFF_FIM + ((size_t)(mp - 256) * 256 + t) * 32 + cn] = v;
    }
  }
}

// ---------------- repack fp32 F -> legfwd B-frags (coalesced v8s stores) ----------------
__global__ void k_repack_bf2(float* ws) { // grid 2048 x 256
  int gid = blockIdx.x * 256 + threadIdx.x;   // < 524288
  int lane = gid & 63, nt = (gid >> 6) & 3, ks = (gid >> 8) & 7, m = gid >> 11;
  int cp = nt * 16 + (lane & 15);
  int tB = ks * 32 + ((lane >> 4) << 3);
  const float* src = ws + (cp < 32 ? OFF_FRE : OFF_FIM) + ((size_t)m * 256 + tB) * 32 + (cp & 31);
  v8s tmp;
#pragma unroll
  for (int t8 = 0; t8 < 8; ++t8) tmp[t8] = f2bf(src[(size_t)t8 * 32]);
  ((v8s*)(ws + OFF_BF2))[gid] = tmp;
}

// ---------------- forward Legendre MFMA: flm[m][l][c] fp32 ----------------
__global__ __launch_bounds__(256) void k_legfwd(float* ws) { // grid (2, 256)
  int half = blockIdx.x, m = blockIdx.y;
  int tid = threadIdx.x, wave = tid >> 6, lane = tid & 63;
  const v8s* A = (const v8s*)(ws + OFF_PA) + (size_t)m * 8192;
  const v8s* B = (const v8s*)(ws + OFF_BF2) + (size_t)m * 2048;
  int mt0 = half * 8 + wave * 2;
  v4f acc[2][4];
#pragma unroll
  for (int i = 0; i < 2; ++i)
#pragma unroll
    for (int n = 0; n < 4; ++n) acc[i][n] = (v4f){0.f, 0.f, 0.f, 0.f};
  bool sk0 = (mt0 * 16 + 15) < m;
  bool sk1 = (mt0 * 16 + 31) < m;
  if (!(sk0 && sk1)) {
    for (int ks = 0; ks < 8; ++ks) {
      v8s b0 = B[ks * 256 + lane];
      v8s b1 = B[ks * 256 + 64 + lane];
      v8s b2 = B[ks * 256 + 128 + lane];
      v8s b3 = B[ks * 256 + 192 + lane];
      if (!sk0) {
        v8s a = A[(size_t)mt0 * 512 + ks * 64 + lane];
        acc[0][0] = __builtin_amdgcn_mfma_f32_16x16x32_bf16(a, b0, acc[0][0], 0, 0, 0);
        acc[0][1] = __builtin_amdgcn_mfma_f32_16x16x32_bf16(a, b1, acc[0][1], 0, 0, 0);
        acc[0][2] = __builtin_amdgcn_mfma_f32_16x16x32_bf16(a, b2, acc[0][2], 0, 0, 0);
        acc[0][3] = __builtin_amdgcn_mfma_f32_16x16x32_bf16(a, b3, acc[0][3], 0, 0, 0);
      }
      if (!sk1) {
        v8s a = A[(size_t)(mt0 + 1) * 512 + ks * 64 + lane];
        acc[1][0] = __builtin_amdgcn_mfma_f32_16x16x32_bf16(a, b0, acc[1][0], 0, 0, 0);
        acc[1][1] = __builtin_amdgcn_mfma_f32_16x16x32_bf16(a, b1, acc[1][1], 0, 0, 0);
        acc[1][2] = __builtin_amdgcn_mfma_f32_16x16x32_bf16(a, b2, acc[1][2], 0, 0, 0);
        acc[1][3] = __builtin_amdgcn_mfma_f32_16x16x32_bf16(a, b3, acc[1][3], 0, 0, 0);
      }
    }
  }
  int quad = lane >> 4, cl = lane & 15;
#pragma unroll
  for (int i = 0; i < 2; ++i) {
    bool sk = i ? sk1 : sk0;
#pragma unroll
    for (int n = 0; n < 4; ++n) {
      int cp = n * 16 + cl;
      float* dst = ws + ((cp >= 32) ? OFF_SFIM : OFF_SFRE) + (size_t)m * 8192 + (cp & 31);
#pragma unroll
      for (int r = 0; r < 4; ++r) {
        int l = (mt0 + i) * 16 + quad * 4 + r;
        dst[(size_t)l * 32] = sk ? 0.f : acc[i][n][r];
      }
    }
  }
}

// ---------------- bilinear (antialias) resize, fused 2-D taps ----------------
__global__ __launch_bounds__(256) void k_resize(float* ws) { // grid 4080 x 256
  int tid = threadIdx.x;
  int p = blockIdx.x * 8 + (tid >> 5);
  int c = tid & 31;
  int lp = p & 127, jp = p >> 7;
  const float* WLW = ws + OFF_WLW;
  const int* WLI = (const int*)(ws + OFF_WLI);
  const float* WMW = ws + OFF_WMW;
  const int* WMI = (const int*)(ws + OFF_WMI);
  const float* SFRE = ws + OFF_SFRE;
  const float* SFIM = ws + OFF_SFIM;
  float accr = 0.f, acci = 0.f;
  for (int b = 0; b < 6; ++b) {
    float wm = WMW[jp * 6 + b];
    int jm = WMI[jp * 6 + b];
    bool mneg = (jm < 255);
    int mm = mneg ? (255 - jm) : (jm - 255);
    float fre_f = (mneg && (mm & 1)) ? -1.f : 1.f;
    float fim_f = mneg ? -fre_f : 1.f;
#pragma unroll
    for (int a = 0; a < 4; ++a) {
      float w = wm * WLW[lp * 4 + a];
      int li = WLI[lp * 4 + a];
      size_t base = ((size_t)mm * 256 + li) * 32 + c;
      accr = fmaf(w * fre_f, SFRE[base], accr);
      acci = fmaf(w * fim_f, SFIM[base], acci);
    }
  }
  ws[OFF_RRE + ((size_t)jp * 128 + lp) * 32 + c] = accr;
  ws[OFF_RIM + ((size_t)jp * 128 + lp) * 32 + c] = acci;
}

// ---------------- per-l complex channel mix -> fp32 C[j][l][c] (coalesced) ----------------
__global__ __launch_bounds__(256) void k_conv(float* ws) { // grid (4 jq, 128 l) x 256
  int jq = blockIdx.x, l = blockIdx.y;
  int tid = threadIdx.x;
  int jl = tid >> 5, o = tid & 31;
  __shared__ __align__(16) float wr[32 * 36];
  __shared__ __align__(16) float wi[32 * 36];
  __shared__ __align__(16) float fr[8 * 32];
  __shared__ __align__(16) float fi[8 * 32];
  {
    int oo = tid >> 3, i4 = (tid & 7) * 4;
    *(float4*)(wr + oo * 36 + i4) = ld4(ws + OFF_WPR + ((size_t)l * 32 + oo) * 32 + i4);
    *(float4*)(wi + oo * 36 + i4) = ld4(ws + OFF_WPI + ((size_t)l * 32 + oo) * 32 + i4);
  }
  for (int ji = 0; ji < 8; ++ji) {
    int j = jq * 64 + ji * 8 + jl;
    int jc = (j < 255) ? j : 254;
    __syncthreads();
    size_t fbase = ((size_t)jc * 128 + l) * 32;
    fr[jl * 32 + o] = ws[OFF_RRE + fbase + o];
    fi[jl * 32 + o] = ws[OFF_RIM + fbase + o];
    __syncthreads();
    float accr = 0.f, acci = 0.f;
#pragma unroll
    for (int i0 = 0; i0 < 32; i0 += 4) {
      float4 f_r = *(const float4*)(fr + jl * 32 + i0);
      float4 f_i = *(const float4*)(fi + jl * 32 + i0);
      float4 w_r = *(const float4*)(wr + o * 36 + i0);
      float4 w_i = *(const float4*)(wi + o * 36 + i0);
      accr += f_r.x * w_r.x - f_i.x * w_i.x;  acci += f_r.x * w_i.x + f_i.x * w_r.x;
      accr += f_r.y * w_r.y - f_i.y * w_i.y;  acci += f_r.y * w_i.y + f_i.y * w_r.y;
      accr += f_r.z * w_r.z - f_i.z * w_i.z;  acci += f_r.z * w_i.z + f_i.z * w_r.z;
      accr += f_r.w * w_r.w - f_i.w * w_i.w;  acci += f_r.w * w_i.w + f_i.w * w_r.w;
    }
    if (j < 255) {
      float s = (j < 127 && ((127 - j) & 1)) ? -1.f : 1.f;   // (-1)^|m| for negative m
      ws[OFF_CRE + ((size_t)j * 128 + l) * 32 + o] = s * accr;
      ws[OFF_CIM + ((size_t)j * 128 + l) * 32 + o] = s * acci;
    }
  }
}

// ---------------- repack fp32 C -> leginv B-frags (coalesced v8s stores) ----------------
__global__ void k_repack_bi2(float* ws) { // grid 4080 x 256
  int gid = blockIdx.x * 256 + threadIdx.x;   // < 1044480
  int lane = gid & 63, nt = (gid >> 6) & 3, ks = (gid >> 8) & 3, j = gid >> 10;
  int cp = nt * 16 + (lane & 15);
  int lB = ks * 32 + ((lane >> 4) << 3);
  const float* src = ws + (cp < 32 ? OFF_CRE : OFF_CIM) + ((size_t)j * 128 + lB) * 32 + (cp & 31);
  v8s tmp;
#pragma unroll
  for (int l8 = 0; l8 < 8; ++l8) tmp[l8] = f2bf(src[(size_t)l8 * 32]);
  ((v8s*)(ws + OFF_BI2))[gid] = tmp;
}

// ---------------- inverse Legendre MFMA -> fp32 G[t][j][c] (coalesced epilogue) ----------------
__global__ __launch_bounds__(256) void k_gemm_linv(float* ws) { // grid (2, 255)
  int half = blockIdx.x, j = blockIdx.y;
  int d = j - 127; int mm = (d < 0) ? -d : d;
  int tid = threadIdx.x, wave = tid >> 6, lane = tid & 63;
  const v8s* A = (const v8s*)(ws + OFF_PT) + (size_t)mm * 8192;
  const v8s* B = (const v8s*)(ws + OFF_BI2) + (size_t)j * 1024;
  int mt0 = half * 8 + wave * 2;
  v4f acc[2][4];
#pragma unroll
  for (int i = 0; i < 2; ++i)
#pragma unroll
    for (int n = 0; n < 4; ++n) acc[i][n] = (v4f){0.f, 0.f, 0.f, 0.f};
  int ks0 = mm >> 5;
  for (int ks = ks0; ks < 4; ++ks) {   // l<128 only (padded flm zero above)
    v8s b0 = B[ks * 256 + lane];
    v8s b1 = B[ks * 256 + 64 + lane];
    v8s b2 = B[ks * 256 + 128 + lane];
    v8s b3 = B[ks * 256 + 192 + lane];
    v8s a0 = A[(size_t)mt0 * 512 + ks * 64 + lane];
    v8s a1 = A[(size_t)(mt0 + 1) * 512 + ks * 64 + lane];
    acc[0][0] = __builtin_amdgcn_mfma_f32_16x16x32_bf16(a0, b0, acc[0][0], 0, 0, 0);
    acc[0][1] = __builtin_amdgcn_mfma_f32_16x16x32_bf16(a0, b1, acc[0][1], 0, 0, 0);
    acc[0][2] = __builtin_amdgcn_mfma_f32_16x16x32_bf16(a0, b2, acc[0][2], 0, 0, 0);
    acc[0][3] = __builtin_amdgcn_mfma_f32_16x16x32_bf16(a0, b3, acc[0][3], 0, 0, 0);
    acc[1][0] = __builtin_amdgcn_mfma_f32_16x16x32_bf16(a1, b0, acc[1][0], 0, 0, 0);
    acc[1][1] = __builtin_amdgcn_mfma_f32_16x16x32_bf16(a1, b1, acc[1][1], 0, 0, 0);
    acc[1][2] = __builtin_amdgcn_mfma_f32_16x16x32_bf16(a1, b2, acc[1][2], 0, 0, 0);
    acc[1][3] = __builtin_amdgcn_mfma_f32_16x16x32_bf16(a1, b3, acc[1][3], 0, 0, 0);
  }
  int quad = lane >> 4, cl = lane & 15;
#pragma unroll
  for (int i = 0; i < 2; ++i) {
#pragma unroll
    for (int n = 0; n < 4; ++n) {
      int cp = n * 16 + cl;
      float* dst = ws + ((cp >= 32) ? OFF_GIM : OFF_GRE) + (size_t)(cp & 31);
#pragma unroll
      for (int r = 0; r < 4; ++r) {
        int t = (mt0 + i) * 16 + quad * 4 + r;
        dst[((size_t)t * 255 + j) * 32] = acc[i][n][r];
      }
    }
  }
}

// ---------------- repack fp32 G -> inv-DFT B-frags (coalesced v8s stores) ----------------
__global__ void k_bfrag_i(float* ws) { // grid 2048 x 256
  int gid = blockIdx.x * 256 + threadIdx.x;   // < 524288
  int lane = gid & 63, nt = (gid >> 6) & 1, ks = (gid >> 7) & 15, t = gid >> 11;
  int c = nt * 16 + (lane & 15);
  int kB = ks * 32 + ((lane >> 4) << 3);
  const float* GRE = ws + OFF_GRE;
  const float* GIM = ws + OFF_GIM;
  v8s tmp;
#pragma unroll
  for (int j8 = 0; j8 < 8; ++j8) {
    int k = kB + j8;
    float v = 0.f;
    if (k < 255)      v = GRE[((size_t)t * 255 + k) * 32 + c];
    else if (k < 510) v = GIM[((size_t)t * 255 + (k - 255)) * 32 + c];
    tmp[j8] = f2bf(v);
  }
  ((v8s*)(ws + OFF_BI))[gid] = tmp;
}

// ---------------- inverse DFT MFMA GEMM -> out ----------------
__global__ __launch_bounds__(256) void k_gemm_i(const float* ws, float* out) { // grid (2, 256)
  int nt = blockIdx.x, t = blockIdx.y;
  int tid = threadIdx.x, wave = tid >> 6, lane = tid & 63;
  const v8s* A = (const v8s*)(ws + OFF_AI);
  const v8s* B = (const v8s*)(ws + OFF_BI);
  int mtB = wave * 8;
  v4f acc[8];
#pragma unroll
  for (int i = 0; i < 8; ++i) acc[i] = (v4f){0.f, 0.f, 0.f, 0.f};
  for (int ks = 0; ks < 16; ++ks) {
    v8s b = B[(size_t)((t * 16 + ks) * 2 + nt) * 64 + lane];
#pragma unroll
    for (int i = 0; i < 8; ++i) {
      v8s a = A[(size_t)((mtB + i) * 16 + ks) * 64 + lane];
      acc[i] = __builtin_amdgcn_mfma_f32_16x16x32_bf16(a, b, acc[i], 0, 0, 0);
    }
  }
  int quad = lane >> 4, cn = nt * 16 + (lane & 15);
#pragma unroll
  for (int i = 0; i < 8; ++i) {
    int mt = mtB + i;
#pragma unroll
    for (int r = 0; r < 4; ++r) {
      int phi = mt * 16 + quad * 4 + r;
      if (phi < 511) out[((size_t)t * 511 + phi) * 32 + cn] = acc[i][r];
    }
  }
}

// ---------------- launch ----------------
extern "C" void kernel_launch(void* const* d_in, const int* in_sizes, int n_in,
                              void* d_out, int out_size, void* d_ws, size_t ws_size,
                              hipStream_t stream) {
  const float* x = (const float*)d_in[0];
  const float* t_emb = (const float*)d_in[1];
  const float* w_real = (const float*)d_in[2];
  const float* w_imag = (const float*)d_in[3];
  const float* w_tr = (const float*)d_in[4];
  const float* b_tr = (const float*)d_in[5];
  const float* w_ti = (const float*)d_in[6];
  const float* b_ti = (const float*)d_in[7];
  float* ws = (float*)d_ws;
  float* out = (float*)d_out;
  (void)in_sizes; (void)n_in; (void)out_size; (void)ws_size; // needs ~112 MB workspace

  hipLaunchKernelGGL(k_setup_small, dim3(1), dim3(256), 0, stream,
                     t_emb, w_tr, b_tr, w_ti, b_ti, ws);
  hipLaunchKernelGGL(k_wprep, dim3(512), dim3(256), 0, stream, w_real, w_imag, ws);
  hipLaunchKernelGGL(k_legendre, dim3(256), dim3(256), 0, stream, ws);
  hipLaunchKernelGGL(k_atab, dim3(2048), dim3(256), 0, stream, ws);
  hipLaunchKernelGGL(k_bfrag_f, dim3(2048), dim3(256), 0, stream, x, ws);
  hipLaunchKernelGGL(k_gemm_f, dim3(2, 256), dim3(256), 0, stream, ws);
  hipLaunchKernelGGL(k_repack_bf2, dim3(2048), dim3(256), 0, stream, ws);
  hipLaunchKernelGGL(k_legfwd, dim3(2, 256), dim3(256), 0, stream, ws);
  hipLaunchKernelGGL(k_resize, dim3(4080), dim3(256), 0, stream, ws);
  hipLaunchKernelGGL(k_conv, dim3(4, 128), dim3(256), 0, stream, ws);
  hipLaunchKernelGGL(k_repack_bi2, dim3(4080), dim3(256), 0, stream, ws);
  hipLaunchKernelGGL(k_gemm_linv, dim3(2, 255), dim3(256), 0, stream, ws);
  hipLaunchKernelGGL(k_bfrag_i, dim3(2048), dim3(256), 0, stream, ws);
  hipLaunchKernelGGL(k_gemm_i, dim3(2, 256), dim3(256), 0, stream, ws, out);
}

// Round 8
// 230.003 us; speedup vs baseline: 1.1377x; 1.1377x over previous
//
#include <hip/hip_runtime.h>
#include <math.h>

#define PI_D 3.14159265358979323846

typedef short v8s __attribute__((ext_vector_type(8)));
typedef float v4f __attribute__((ext_vector_type(4)));

// ---------------- workspace layout (float offsets), total 23327232 floats = 93.3 MB ----------------
constexpr size_t OFF_PA   = 0;                   // legfwd A-frags bf16: per m, A[l][t]  (256 slices, 32 MB)
constexpr size_t OFF_PT   = 8388608;             // leginv A-frags bf16: per m<128, A[t][l] (16 MB)
constexpr size_t OFF_SFRE = 12582912;            // flm re [m][l][c] fp32 (8.4 MB)
constexpr size_t OFF_SFIM = 14680064;            // flm im
constexpr size_t OFF_FRE  = 16777216;            // fwd-DFT out fp32 F[m][t][c] (8.4 MB)
constexpr size_t OFF_FIM  = 18874368;
constexpr size_t OFF_CRE  = 20971520;            // conv out fp32 [j][l][c] (4.2 MB)
constexpr size_t OFF_CIM  = 22016000;
constexpr size_t OFF_AF   = 23060480;            // fwd DFT A-frags bf16 (512 KB)
constexpr size_t OFF_AI   = 23191552;            // inv DFT A-frags bf16 (512 KB)
constexpr size_t OFF_WQ   = 23322624;            // 256 quadrature weights
constexpr size_t OFF_TC   = 23322880;            // 256 (t_cplx re|im)
constexpr size_t OFF_WLW  = 23323136;            // 128*4 l-resize weights
constexpr size_t OFF_WLI  = 23323648;            // 128*4 l-resize indices (int)
constexpr size_t OFF_WMW  = 23324160;            // 255*6 m-resize weights
constexpr size_t OFF_WMI  = 23325696;            // 255*6 m-resize indices (int)
// overlays (lifetimes disjoint):
constexpr size_t OFF_GRE  = OFF_FRE;             // G fp32 [t][j][c] (F dead after legfwd; 2088960 <= 2097152)
constexpr size_t OFF_GIM  = OFF_FIM;

__device__ __forceinline__ short f2bf(float f) {   // RTNE float->bf16 bits
  unsigned u = __float_as_uint(f);
  unsigned r = (u + 0x7FFFu + ((u >> 16) & 1u)) >> 16;
  return (short)r;
}

// ---------------- prep: DFT A-frag tables (fast fp32 trig) + setup block ----------------
__global__ void k_prep(const float* t_emb, const float* w_tr, const float* b_tr,
                       const float* w_ti, const float* b_ti, float* ws) { // grid 2049 x 256
  int bx = blockIdx.x, tid = threadIdx.x;
  if (bx < 2048) {
    int g = bx * 256 + tid;
    bool inv = (g >= 262144);
    int gid = inv ? g - 262144 : g;
    int j = gid & 7, lane = (gid >> 3) & 63, ks = (gid >> 9) & 15, mt = gid >> 13;
    int m = mt * 16 + (lane & 15);
    int k = ks * 32 + ((lane >> 4) << 3) + j;
    float v = 0.f;
    if (!inv) {
      if (k < 511) {
        int mm = (m < 256) ? m : m - 256;
        int kk = (mm * k) % 511;
        float ang = (float)(2.0 * PI_D / 511.0) * (float)kk;
        float s, c; __sincosf(ang, &s, &c);
        v = (m < 256) ? c : -s;
      }
      ((short*)(ws + OFF_AF))[gid] = f2bf(v);
    } else {
      if (m < 511 && k < 510) {
        int jj = (k < 255) ? k : k - 255;
        int jm = jj - 127;
        int kk = ((jm * m) % 511 + 511) % 511;
        float ang = (float)(2.0 * PI_D / 511.0) * (float)kk;
        float s, c; __sincosf(ang, &s, &c);
        v = (k < 255) ? c : -s;
      }
      ((short*)(ws + OFF_AI))[gid] = f2bf(v);
    }
    return;
  }
  // setup block (quadrature, t_cplx, resize taps)
  if (tid < 256) {
    double theta = PI_D * (2.0 * tid + 1.0) / 511.0;
    double dang = 2.0 * PI_D / 511.0;
    ws[OFF_WQ + tid] = (float)(sin(theta) * dang * dang);
  }
  {
    int h = tid >> 7, o = tid & 127;
    const float* W = h ? w_ti : w_tr;
    float s = h ? b_ti[o] : b_tr[o];
    for (int T = 0; T < 256; ++T) s += t_emb[T] * W[T * 128 + o];
    ws[OFF_TC + h * 128 + o] = s;
  }
  if (tid < 128) {
    double sf = 2.0 * tid + 0.5;
    double wv[4]; int iv[4]; double wsum = 0.0;
    for (int a = 0; a < 4; ++a) {
      int t = 2 * tid - 1 + a;
      double r = 1.0 - fabs(sf - (double)t) * 0.5;
      bool valid = (t >= 0 && t < 256 && r > 0.0);
      wv[a] = valid ? r : 0.0; iv[a] = valid ? t : 0;
      wsum += wv[a];
    }
    for (int a = 0; a < 4; ++a) {
      ws[OFF_WLW + tid * 4 + a] = (float)(wv[a] / wsum);
      ((int*)(ws + OFF_WLI))[tid * 4 + a] = iv[a];
    }
  }
  if (tid < 255) {
    double inv2 = 511.0 / 255.0;
    double sf = (tid + 0.5) * inv2 - 0.5;
    int t0 = (int)floor(sf) - 2;
    double wv[6]; int iv[6]; double wsum = 0.0;
    for (int b = 0; b < 6; ++b) {
      int t = t0 + b;
      double r = 1.0 - fabs(sf - (double)t) * (255.0 / 511.0);
      bool valid = (t >= 0 && t < 511 && r > 0.0);
      wv[b] = valid ? r : 0.0; iv[b] = valid ? t : 0;
      wsum += wv[b];
    }
    for (int b = 0; b < 6; ++b) {
      ws[OFF_WMW + tid * 6 + b] = (float)(wv[b] / wsum);
      ((int*)(ws + OFF_WMI))[tid * 6 + b] = iv[b];
    }
  }
}

// ---------------- Legendre basis -> bf16 MFMA A-frag tables (LDS-staged, coalesced) ----------------
__global__ __launch_bounds__(256) void k_legendre(float* ws) {   // grid 256 (m) x 256 (t)
  int m = blockIdx.x, t = threadIdx.x;
  __shared__ double cA[256], cB[256], cS[256];
  {
    int l = t;
    if (l >= 1) cS[l] = -sqrt((2.0 * l + 1.0) / (2.0 * l));
    if (l >= m + 2) {
      double ll = l, mm = m;
      double den = ll * ll - mm * mm;
      cA[l] = sqrt((4.0 * ll * ll - 1.0) / den);
      cB[l] = sqrt((2.0 * ll + 1.0) * (ll - 1.0 - mm) * (ll - 1.0 + mm) /
                   ((2.0 * ll - 3.0) * den));
    }
  }
  __syncthreads();
  __shared__ short tile[16 * 280];
  __shared__ short tileT[256 * 34];
  bool wantPT = (m < 128);
  short* PAp = (short*)(ws + OFF_PA) + (size_t)m * 65536;
  short* PTp = (short*)(ws + OFF_PT) + (size_t)m * 65536;
  double theta = PI_D * (2.0 * t + 1.0) / 511.0;
  double ct = cos(theta), st = sin(theta);
  double p0 = sqrt(1.0 / (4.0 * PI_D));
  for (int k = 1; k <= m; ++k) p0 *= cS[k] * st;
  double pm1 = 0.0, pcur = 0.0;
  for (int lt = 0; lt < 16; ++lt) {
    for (int li = 0; li < 16; ++li) {
      int l = lt * 16 + li;
      float v;
      if (l < m) v = 0.f;
      else if (l == m) { pcur = p0; v = (float)pcur; }
      else if (l == m + 1) { pm1 = pcur; pcur = sqrt(2.0 * m + 3.0) * ct * pm1; v = (float)pcur; }
      else { double p2 = cA[l] * ct * pcur - cB[l] * pm1; pm1 = pcur; pcur = p2; v = (float)p2; }
      short bv = f2bf(v);
      tile[li * 280 + t] = bv;
      if (wantPT) tileT[t * 34 + li] = bv;
    }
    __syncthreads();
#pragma unroll
    for (int pass = 0; pass < 2; ++pass) {
      int ch = pass * 256 + t;
      int li = ch & 15, T0 = ch >> 4;
      size_t dst = (size_t)lt * 4096 + (size_t)(T0 >> 2) * 512 + (size_t)((T0 & 3) * 16 + li) * 8;
      *(v8s*)(PAp + dst) = *(const v8s*)(tile + li * 280 + T0 * 8);
    }
    if (wantPT) {
#pragma unroll
      for (int pass = 0; pass < 2; ++pass) {
        int ch = pass * 256 + t;
        int tt = ch >> 1, li0 = (ch & 1) * 8;
        size_t dst = (size_t)(tt >> 4) * 4096 + (size_t)(lt >> 1) * 512 +
                     (size_t)(((lt & 1) * 2 + (li0 >> 3)) * 16 + (tt & 15)) * 8;
        const int* src = (const int*)(tileT + tt * 34 + li0);
        int* d = (int*)(PTp + dst);
        d[0] = src[0]; d[1] = src[1]; d[2] = src[2]; d[3] = src[3];
      }
    }
    __syncthreads();
  }
}

// ---------------- fwd DFT MFMA GEMM (inline x -> B-frags) -> fp32 F[m][t][c] ----------------
__global__ __launch_bounds__(256) void k_gemm_f(const float* x, float* ws) { // grid (2, 256)
  int nt = blockIdx.x, t = blockIdx.y;
  int tid = threadIdx.x, wave = tid >> 6, lane = tid & 63;
  const v8s* A = (const v8s*)(ws + OFF_AF);
  float wq = ws[OFF_WQ + t];
  const float* xb = x + (size_t)t * 511 * 32 + nt * 16 + (lane & 15);
  int phiB = (lane >> 4) << 3;
  int mtB = wave * 8;
  v4f acc[8];
#pragma unroll
  for (int i = 0; i < 8; ++i) acc[i] = (v4f){0.f, 0.f, 0.f, 0.f};
  for (int ks = 0; ks < 16; ++ks) {
    v8s b;
    int phi0 = ks * 32 + phiB;
#pragma unroll
    for (int j = 0; j < 8; ++j) {
      int phi = phi0 + j;
      float v = (phi < 511) ? wq * xb[(size_t)phi * 32] : 0.f;
      b[j] = f2bf(v);
    }
#pragma unroll
    for (int i = 0; i < 8; ++i) {
      v8s a = A[(size_t)((mtB + i) * 16 + ks) * 64 + lane];
      acc[i] = __builtin_amdgcn_mfma_f32_16x16x32_bf16(a, b, acc[i], 0, 0, 0);
    }
  }
  int quad = lane >> 4, cn = nt * 16 + (lane & 15);
#pragma unroll
  for (int i = 0; i < 8; ++i) {
    int mt = mtB + i;
#pragma unroll
    for (int r = 0; r < 4; ++r) {
      int mp = mt * 16 + quad * 4 + r;
      float v = acc[i][r];
      if (mp < 256) ws[OFF_FRE + ((size_t)mp * 256 + t) * 32 + cn] = v;
      else          ws[OFF_FIM + ((size_t)(mp - 256) * 256 + t) * 32 + cn] = v;
    }
  }
}

// ---------------- forward Legendre MFMA (inline F -> B-frags): flm[m][l][c] fp32 ----------------
__global__ __launch_bounds__(512) void k_legfwd(float* ws) { // grid 256
  int m = blockIdx.x;
  int tid = threadIdx.x, wave = tid >> 6, lane = tid & 63;
  const v8s* A = (const v8s*)(ws + OFF_PA) + (size_t)m * 8192;
  int mt0 = wave * 2;
  int cl = lane & 15, tB = (lane >> 4) << 3;
  v4f acc[2][4];
#pragma unroll
  for (int i = 0; i < 2; ++i)
#pragma unroll
    for (int n = 0; n < 4; ++n) acc[i][n] = (v4f){0.f, 0.f, 0.f, 0.f};
  bool sk0 = (mt0 * 16 + 15) < m;
  bool sk1 = (mt0 * 16 + 31) < m;
  if (!(sk0 && sk1)) {
    for (int ks = 0; ks < 8; ++ks) {
      int t0 = ks * 32 + tB;
      v8s b[4];
#pragma unroll
      for (int n = 0; n < 4; ++n) {
        int cp = n * 16 + cl;
        const float* Fb = ws + (cp < 32 ? OFF_FRE : OFF_FIM) +
                          (size_t)m * 8192 + (size_t)t0 * 32 + (cp & 31);
#pragma unroll
        for (int j = 0; j < 8; ++j) b[n][j] = f2bf(Fb[(size_t)j * 32]);
      }
      if (!sk0) {
        v8s a = A[(size_t)mt0 * 512 + ks * 64 + lane];
        acc[0][0] = __builtin_amdgcn_mfma_f32_16x16x32_bf16(a, b[0], acc[0][0], 0, 0, 0);
        acc[0][1] = __builtin_amdgcn_mfma_f32_16x16x32_bf16(a, b[1], acc[0][1], 0, 0, 0);
        acc[0][2] = __builtin_amdgcn_mfma_f32_16x16x32_bf16(a, b[2], acc[0][2], 0, 0, 0);
        acc[0][3] = __builtin_amdgcn_mfma_f32_16x16x32_bf16(a, b[3], acc[0][3], 0, 0, 0);
      }
      if (!sk1) {
        v8s a = A[(size_t)(mt0 + 1) * 512 + ks * 64 + lane];
        acc[1][0] = __builtin_amdgcn_mfma_f32_16x16x32_bf16(a, b[0], acc[1][0], 0, 0, 0);
        acc[1][1] = __builtin_amdgcn_mfma_f32_16x16x32_bf16(a, b[1], acc[1][1], 0, 0, 0);
        acc[1][2] = __builtin_amdgcn_mfma_f32_16x16x32_bf16(a, b[2], acc[1][2], 0, 0, 0);
        acc[1][3] = __builtin_amdgcn_mfma_f32_16x16x32_bf16(a, b[3], acc[1][3], 0, 0, 0);
      }
    }
  }
  int quad = lane >> 4;
#pragma unroll
  for (int i = 0; i < 2; ++i) {
    bool sk = i ? sk1 : sk0;
#pragma unroll
    for (int n = 0; n < 4; ++n) {
      int cp = n * 16 + cl;
      float* dst = ws + ((cp >= 32) ? OFF_SFIM : OFF_SFRE) + (size_t)m * 8192 + (cp & 31);
#pragma unroll
      for (int r = 0; r < 4; ++r) {
        int l = (mt0 + i) * 16 + quad * 4 + r;
        dst[(size_t)l * 32] = sk ? 0.f : acc[i][n][r];
      }
    }
  }
}

// ---------------- conv (inline resize + inline weight premult) -> fp32 C[j][l][c] ----------------
__global__ __launch_bounds__(256) void k_conv(const float* w_real, const float* w_imag, float* ws) {
  // grid (4 jq, 128 l) x 256
  int jq = blockIdx.x, l = blockIdx.y;
  int tid = threadIdx.x;
  int jl = tid >> 5, o = tid & 31;
  __shared__ __align__(16) float wr[32 * 36];
  __shared__ __align__(16) float wi[32 * 36];
  __shared__ __align__(16) float fr[8 * 32];
  __shared__ __align__(16) float fi[8 * 32];
  {
    int oo = tid >> 3, i4 = (tid & 7) * 4;
    float tcr = ws[OFF_TC + l], tci = ws[OFF_TC + 128 + l];
#pragma unroll
    for (int q = 0; q < 4; ++q) {
      int i = i4 + q;
      float a = w_real[(size_t)l * 1024 + i * 32 + oo];
      float b = w_imag[(size_t)l * 1024 + i * 32 + oo];
      wr[oo * 36 + i] = tcr * a - tci * b;
      wi[oo * 36 + i] = tcr * b + tci * a;
    }
  }
  const float* SFRE = ws + OFF_SFRE;
  const float* SFIM = ws + OFF_SFIM;
  const float* WMW = ws + OFF_WMW;
  const int* WMI = (const int*)(ws + OFF_WMI);
  float wl[4]; int liv[4];
#pragma unroll
  for (int a = 0; a < 4; ++a) {
    wl[a] = ws[OFF_WLW + l * 4 + a];
    liv[a] = ((const int*)(ws + OFF_WLI))[l * 4 + a];
  }
  for (int ji = 0; ji < 8; ++ji) {
    int j = jq * 64 + ji * 8 + jl;
    int jp = (j < 255) ? j : 254;
    // inline resize for (jp, l, c=o)
    float accr = 0.f, acci = 0.f;
    for (int b = 0; b < 6; ++b) {
      float wm = WMW[jp * 6 + b];
      int jm = WMI[jp * 6 + b];
      bool mneg = (jm < 255);
      int mm = mneg ? (255 - jm) : (jm - 255);
      float fre_f = (mneg && (mm & 1)) ? -1.f : 1.f;
      float fim_f = mneg ? -fre_f : 1.f;
#pragma unroll
      for (int a = 0; a < 4; ++a) {
        float w = wm * wl[a];
        size_t base = ((size_t)mm * 256 + liv[a]) * 32 + o;
        accr = fmaf(w * fre_f, SFRE[base], accr);
        acci = fmaf(w * fim_f, SFIM[base], acci);
      }
    }
    __syncthreads();
    fr[jl * 32 + o] = accr;
    fi[jl * 32 + o] = acci;
    __syncthreads();
    float sr = 0.f, si = 0.f;
#pragma unroll
    for (int i0 = 0; i0 < 32; i0 += 4) {
      float4 f_r = *(const float4*)(fr + jl * 32 + i0);
      float4 f_i = *(const float4*)(fi + jl * 32 + i0);
      float4 w_r = *(const float4*)(wr + o * 36 + i0);
      float4 w_i = *(const float4*)(wi + o * 36 + i0);
      sr += f_r.x * w_r.x - f_i.x * w_i.x;  si += f_r.x * w_i.x + f_i.x * w_r.x;
      sr += f_r.y * w_r.y - f_i.y * w_i.y;  si += f_r.y * w_i.y + f_i.y * w_r.y;
      sr += f_r.z * w_r.z - f_i.z * w_i.z;  si += f_r.z * w_i.z + f_i.z * w_r.z;
      sr += f_r.w * w_r.w - f_i.w * w_i.w;  si += f_r.w * w_i.w + f_i.w * w_r.w;
    }
    if (j < 255) {
      float s = (j < 127 && ((127 - j) & 1)) ? -1.f : 1.f;   // (-1)^|m| for negative m
      ws[OFF_CRE + ((size_t)j * 128 + l) * 32 + o] = s * sr;
      ws[OFF_CIM + ((size_t)j * 128 + l) * 32 + o] = s * si;
    }
  }
}

// ---------------- inverse Legendre MFMA (inline C -> B-frags) -> fp32 G[t][j][c] ----------------
__global__ __launch_bounds__(512) void k_gemm_linv(float* ws) { // grid 255
  int j = blockIdx.x;
  int d = j - 127; int mm = (d < 0) ? -d : d;
  int tid = threadIdx.x, wave = tid >> 6, lane = tid & 63;
  const v8s* A = (const v8s*)(ws + OFF_PT) + (size_t)mm * 8192;
  int mt0 = wave * 2;
  int cl = lane & 15, lB = (lane >> 4) << 3;
  v4f acc[2][4];
#pragma unroll
  for (int i = 0; i < 2; ++i)
#pragma unroll
    for (int n = 0; n < 4; ++n) acc[i][n] = (v4f){0.f, 0.f, 0.f, 0.f};
  int ks0 = mm >> 5;
  for (int ks = ks0; ks < 4; ++ks) {   // l<128 only (padded flm zero above)
    int l0 = ks * 32 + lB;
    v8s b[4];
#pragma unroll
    for (int n = 0; n < 4; ++n) {
      int cp = n * 16 + cl;
      const float* Cb = ws + (cp < 32 ? OFF_CRE : OFF_CIM) +
                        ((size_t)j * 128 + l0) * 32 + (cp & 31);
#pragma unroll
      for (int j8 = 0; j8 < 8; ++j8) b[n][j8] = f2bf(Cb[(size_t)j8 * 32]);
    }
    v8s a0 = A[(size_t)mt0 * 512 + ks * 64 + lane];
    v8s a1 = A[(size_t)(mt0 + 1) * 512 + ks * 64 + lane];
    acc[0][0] = __builtin_amdgcn_mfma_f32_16x16x32_bf16(a0, b[0], acc[0][0], 0, 0, 0);
    acc[0][1] = __builtin_amdgcn_mfma_f32_16x16x32_bf16(a0, b[1], acc[0][1], 0, 0, 0);
    acc[0][2] = __builtin_amdgcn_mfma_f32_16x16x32_bf16(a0, b[2], acc[0][2], 0, 0, 0);
    acc[0][3] = __builtin_amdgcn_mfma_f32_16x16x32_bf16(a0, b[3], acc[0][3], 0, 0, 0);
    acc[1][0] = __builtin_amdgcn_mfma_f32_16x16x32_bf16(a1, b[0], acc[1][0], 0, 0, 0);
    acc[1][1] = __builtin_amdgcn_mfma_f32_16x16x32_bf16(a1, b[1], acc[1][1], 0, 0, 0);
    acc[1][2] = __builtin_amdgcn_mfma_f32_16x16x32_bf16(a1, b[2], acc[1][2], 0, 0, 0);
    acc[1][3] = __builtin_amdgcn_mfma_f32_16x16x32_bf16(a1, b[3], acc[1][3], 0, 0, 0);
  }
  int quad = lane >> 4;
#pragma unroll
  for (int i = 0; i < 2; ++i) {
#pragma unroll
    for (int n = 0; n < 4; ++n) {
      int cp = n * 16 + cl;
      float* dst = ws + ((cp >= 32) ? OFF_GIM : OFF_GRE) + (size_t)(cp & 31);
#pragma unroll
      for (int r = 0; r < 4; ++r) {
        int t = (mt0 + i) * 16 + quad * 4 + r;
        dst[((size_t)t * 255 + j) * 32] = acc[i][n][r];
      }
    }
  }
}

// ---------------- inverse DFT MFMA GEMM (inline G -> B-frags) -> out ----------------
__global__ __launch_bounds__(256) void k_gemm_i(const float* ws, float* out) { // grid (2, 256)
  int nt = blockIdx.x, t = blockIdx.y;
  int tid = threadIdx.x, wave = tid >> 6, lane = tid & 63;
  const v8s* A = (const v8s*)(ws + OFF_AI);
  const float* GRE = ws + OFF_GRE;
  const float* GIM = ws + OFF_GIM;
  int mtB = wave * 8;
  int cn = nt * 16 + (lane & 15);
  int kB = (lane >> 4) << 3;
  v4f acc[8];
#pragma unroll
  for (int i = 0; i < 8; ++i) acc[i] = (v4f){0.f, 0.f, 0.f, 0.f};
  for (int ks = 0; ks < 16; ++ks) {
    v8s b;
    int k0 = ks * 32 + kB;
#pragma unroll
    for (int j8 = 0; j8 < 8; ++j8) {
      int k = k0 + j8;
      float v = 0.f;
      if (k < 255)      v = GRE[((size_t)t * 255 + k) * 32 + cn];
      else if (k < 510) v = GIM[((size_t)t * 255 + (k - 255)) * 32 + cn];
      b[j8] = f2bf(v);
    }
#pragma unroll
    for (int i = 0; i < 8; ++i) {
      v8s a = A[(size_t)((mtB + i) * 16 + ks) * 64 + lane];
      acc[i] = __builtin_amdgcn_mfma_f32_16x16x32_bf16(a, b, acc[i], 0, 0, 0);
    }
  }
  int quad = lane >> 4;
#pragma unroll
  for (int i = 0; i < 8; ++i) {
    int mt = mtB + i;
#pragma unroll
    for (int r = 0; r < 4; ++r) {
      int phi = mt * 16 + quad * 4 + r;
      if (phi < 511) out[((size_t)t * 511 + phi) * 32 + cn] = acc[i][r];
    }
  }
}

// ---------------- launch ----------------
extern "C" void kernel_launch(void* const* d_in, const int* in_sizes, int n_in,
                              void* d_out, int out_size, void* d_ws, size_t ws_size,
                              hipStream_t stream) {
  const float* x = (const float*)d_in[0];
  const float* t_emb = (const float*)d_in[1];
  const float* w_real = (const float*)d_in[2];
  const float* w_imag = (const float*)d_in[3];
  const float* w_tr = (const float*)d_in[4];
  const float* b_tr = (const float*)d_in[5];
  const float* w_ti = (const float*)d_in[6];
  const float* b_ti = (const float*)d_in[7];
  float* ws = (float*)d_ws;
  float* out = (float*)d_out;
  (void)in_sizes; (void)n_in; (void)out_size; (void)ws_size; // needs ~94 MB workspace

  hipLaunchKernelGGL(k_prep, dim3(2049), dim3(256), 0, stream,
                     t_emb, w_tr, b_tr, w_ti, b_ti, ws);
  hipLaunchKernelGGL(k_legendre, dim3(256), dim3(256), 0, stream, ws);
  hipLaunchKernelGGL(k_gemm_f, dim3(2, 256), dim3(256), 0, stream, x, ws);
  hipLaunchKernelGGL(k_legfwd, dim3(256), dim3(512), 0, stream, ws);
  hipLaunchKernelGGL(k_conv, dim3(4, 128), dim3(256), 0, stream, w_real, w_imag, ws);
  hipLaunchKernelGGL(k_gemm_linv, dim3(255), dim3(512), 0, stream, ws);
  hipLaunchKernelGGL(k_gemm_i, dim3(2, 256), dim3(256), 0, stream, ws, out);
}

// Round 9
// 223.162 us; speedup vs baseline: 1.1726x; 1.0307x over previous
//
#include <hip/hip_runtime.h>
#include <math.h>

#define PI_D 3.14159265358979323846

typedef short v8s __attribute__((ext_vector_type(8)));
typedef float v4f __attribute__((ext_vector_type(4)));

// ---------------- workspace layout (float offsets), total 23327232 floats = 93.3 MB ----------------
constexpr size_t OFF_PA   = 0;                   // legfwd A-frags bf16: per m, A[l][t]  (256 slices, 32 MB)
constexpr size_t OFF_PT   = 8388608;             // leginv A-frags bf16: per m<128, A[t][l] (16 MB)
constexpr size_t OFF_SFRE = 12582912;            // flm re [m][l][c] fp32 (8.4 MB)
constexpr size_t OFF_SFIM = 14680064;            // flm im
constexpr size_t OFF_FRE  = 16777216;            // fwd-DFT out fp32 F[m][t][c] (8.4 MB)
constexpr size_t OFF_FIM  = 18874368;
constexpr size_t OFF_CRE  = 20971520;            // conv out fp32 [j][l][c] (4.2 MB)
constexpr size_t OFF_CIM  = 22016000;
constexpr size_t OFF_AF   = 23060480;            // fwd DFT A-frags bf16 (512 KB)
constexpr size_t OFF_AI   = 23191552;            // inv DFT A-frags bf16 (512 KB)
constexpr size_t OFF_WQ   = 23322624;            // 256 quadrature weights
constexpr size_t OFF_TC   = 23322880;            // 256 (t_cplx re|im)
constexpr size_t OFF_WLW  = 23323136;            // 128*4 l-resize weights
constexpr size_t OFF_WLI  = 23323648;            // 128*4 l-resize indices (int)
constexpr size_t OFF_WMW  = 23324160;            // 255*6 m-resize weights
constexpr size_t OFF_WMI  = 23325696;            // 255*6 m-resize indices (int)
// overlays (lifetimes disjoint):
constexpr size_t OFF_GRE  = OFF_FRE;             // G fp32 [t][j][c] (F dead after legfwd)
constexpr size_t OFF_GIM  = OFF_FIM;

__device__ __forceinline__ short f2bf(float f) {   // RTNE float->bf16 bits
  unsigned u = __float_as_uint(f);
  unsigned r = (u + 0x7FFFu + ((u >> 16) & 1u)) >> 16;
  return (short)r;
}

// ---------------- prep: DFT A-frag tables (fast fp32 trig) + setup block ----------------
__global__ void k_prep(const float* t_emb, const float* w_tr, const float* b_tr,
                       const float* w_ti, const float* b_ti, float* ws) { // grid 2049 x 256
  int bx = blockIdx.x, tid = threadIdx.x;
  if (bx < 2048) {
    int g = bx * 256 + tid;
    bool inv = (g >= 262144);
    int gid = inv ? g - 262144 : g;
    int j = gid & 7, lane = (gid >> 3) & 63, ks = (gid >> 9) & 15, mt = gid >> 13;
    int m = mt * 16 + (lane & 15);
    int k = ks * 32 + ((lane >> 4) << 3) + j;
    float v = 0.f;
    if (!inv) {
      if (k < 511) {
        int mm = (m < 256) ? m : m - 256;
        int kk = (mm * k) % 511;
        float ang = (float)(2.0 * PI_D / 511.0) * (float)kk;
        float s, c; __sincosf(ang, &s, &c);
        v = (m < 256) ? c : -s;
      }
      ((short*)(ws + OFF_AF))[gid] = f2bf(v);
    } else {
      if (m < 511 && k < 510) {
        int jj = (k < 255) ? k : k - 255;
        int jm = jj - 127;
        int kk = ((jm * m) % 511 + 511) % 511;
        float ang = (float)(2.0 * PI_D / 511.0) * (float)kk;
        float s, c; __sincosf(ang, &s, &c);
        v = (k < 255) ? c : -s;
      }
      ((short*)(ws + OFF_AI))[gid] = f2bf(v);
    }
    return;
  }
  if (tid < 256) {
    double theta = PI_D * (2.0 * tid + 1.0) / 511.0;
    double dang = 2.0 * PI_D / 511.0;
    ws[OFF_WQ + tid] = (float)(sin(theta) * dang * dang);
  }
  {
    int h = tid >> 7, o = tid & 127;
    const float* W = h ? w_ti : w_tr;
    float s = h ? b_ti[o] : b_tr[o];
    for (int T = 0; T < 256; ++T) s += t_emb[T] * W[T * 128 + o];
    ws[OFF_TC + h * 128 + o] = s;
  }
  if (tid < 128) {
    double sf = 2.0 * tid + 0.5;
    double wv[4]; int iv[4]; double wsum = 0.0;
    for (int a = 0; a < 4; ++a) {
      int t = 2 * tid - 1 + a;
      double r = 1.0 - fabs(sf - (double)t) * 0.5;
      bool valid = (t >= 0 && t < 256 && r > 0.0);
      wv[a] = valid ? r : 0.0; iv[a] = valid ? t : 0;
      wsum += wv[a];
    }
    for (int a = 0; a < 4; ++a) {
      ws[OFF_WLW + tid * 4 + a] = (float)(wv[a] / wsum);
      ((int*)(ws + OFF_WLI))[tid * 4 + a] = iv[a];
    }
  }
  if (tid < 255) {
    double inv2 = 511.0 / 255.0;
    double sf = (tid + 0.5) * inv2 - 0.5;
    int t0 = (int)floor(sf) - 2;
    double wv[6]; int iv[6]; double wsum = 0.0;
    for (int b = 0; b < 6; ++b) {
      int t = t0 + b;
      double r = 1.0 - fabs(sf - (double)t) * (255.0 / 511.0);
      bool valid = (t >= 0 && t < 511 && r > 0.0);
      wv[b] = valid ? r : 0.0; iv[b] = valid ? t : 0;
      wsum += wv[b];
    }
    for (int b = 0; b < 6; ++b) {
      ws[OFF_WMW + tid * 6 + b] = (float)(wv[b] / wsum);
      ((int*)(ws + OFF_WMI))[tid * 6 + b] = iv[b];
    }
  }
}

// ---------------- Legendre basis -> bf16 MFMA A-frag tables (LDS-staged, coalesced) ----------------
__global__ __launch_bounds__(256) void k_legendre(float* ws) {   // grid 256 (m) x 256 (t)
  int m = blockIdx.x, t = threadIdx.x;
  __shared__ double cA[256], cB[256], cS[256];
  {
    int l = t;
    if (l >= 1) cS[l] = -sqrt((2.0 * l + 1.0) / (2.0 * l));
    if (l >= m + 2) {
      double ll = l, mm = m;
      double den = ll * ll - mm * mm;
      cA[l] = sqrt((4.0 * ll * ll - 1.0) / den);
      cB[l] = sqrt((2.0 * ll + 1.0) * (ll - 1.0 - mm) * (ll - 1.0 + mm) /
                   ((2.0 * ll - 3.0) * den));
    }
  }
  __syncthreads();
  __shared__ short tile[16 * 280];
  __shared__ short tileT[256 * 34];
  bool wantPT = (m < 128);
  short* PAp = (short*)(ws + OFF_PA) + (size_t)m * 65536;
  short* PTp = (short*)(ws + OFF_PT) + (size_t)m * 65536;
  double theta = PI_D * (2.0 * t + 1.0) / 511.0;
  double ct = cos(theta), st = sin(theta);
  double p0 = sqrt(1.0 / (4.0 * PI_D));
  for (int k = 1; k <= m; ++k) p0 *= cS[k] * st;
  double pm1 = 0.0, pcur = 0.0;
  for (int lt = 0; lt < 16; ++lt) {
    for (int li = 0; li < 16; ++li) {
      int l = lt * 16 + li;
      float v;
      if (l < m) v = 0.f;
      else if (l == m) { pcur = p0; v = (float)pcur; }
      else if (l == m + 1) { pm1 = pcur; pcur = sqrt(2.0 * m + 3.0) * ct * pm1; v = (float)pcur; }
      else { double p2 = cA[l] * ct * pcur - cB[l] * pm1; pm1 = pcur; pcur = p2; v = (float)p2; }
      short bv = f2bf(v);
      tile[li * 280 + t] = bv;
      if (wantPT) tileT[t * 34 + li] = bv;
    }
    __syncthreads();
#pragma unroll
    for (int pass = 0; pass < 2; ++pass) {
      int ch = pass * 256 + t;
      int li = ch & 15, T0 = ch >> 4;
      size_t dst = (size_t)lt * 4096 + (size_t)(T0 >> 2) * 512 + (size_t)((T0 & 3) * 16 + li) * 8;
      *(v8s*)(PAp + dst) = *(const v8s*)(tile + li * 280 + T0 * 8);
    }
    if (wantPT) {
#pragma unroll
      for (int pass = 0; pass < 2; ++pass) {
        int ch = pass * 256 + t;
        int tt = ch >> 1, li0 = (ch & 1) * 8;
        size_t dst = (size_t)(tt >> 4) * 4096 + (size_t)(lt >> 1) * 512 +
                     (size_t)(((lt & 1) * 2 + (li0 >> 3)) * 16 + (tt & 15)) * 8;
        const int* src = (const int*)(tileT + tt * 34 + li0);
        int* d = (int*)(PTp + dst);
        d[0] = src[0]; d[1] = src[1]; d[2] = src[2]; d[3] = src[3];
      }
    }
    __syncthreads();
  }
}

// ---------------- fwd DFT MFMA GEMM (prefetched inline B) -> fp32 F[m][t][c] ----------------
// grid (4, 256): nt = bx&1, mh = bx>>1; wave does 4 mt tiles -> 16 waves/CU
__global__ __launch_bounds__(256) void k_gemm_f(const float* x, float* ws) {
  int bx = blockIdx.x, t = blockIdx.y;
  int nt = bx & 1, mh = bx >> 1;
  int tid = threadIdx.x, wave = tid >> 6, lane = tid & 63;
  const v8s* A = (const v8s*)(ws + OFF_AF);
  float wq = ws[OFF_WQ + t];
  const float* xb = x + (size_t)t * 511 * 32 + nt * 16 + (lane & 15);
  int phiB = (lane >> 4) << 3;
  int mtB = mh * 16 + wave * 4;
  v4f acc[4];
#pragma unroll
  for (int i = 0; i < 4; ++i) acc[i] = (v4f){0.f, 0.f, 0.f, 0.f};
  float bv[8];
#pragma unroll
  for (int j = 0; j < 8; ++j) {
    int phi = phiB + j;
    bv[j] = (phi < 511) ? xb[(size_t)phi * 32] : 0.f;
  }
  for (int ks = 0; ks < 16; ++ks) {
    float bn[8];
    if (ks < 15) {
      int phi0 = (ks + 1) * 32 + phiB;
#pragma unroll
      for (int j = 0; j < 8; ++j) {
        int phi = phi0 + j;
        bn[j] = (phi < 511) ? xb[(size_t)phi * 32] : 0.f;
      }
    }
    v8s b;
#pragma unroll
    for (int j = 0; j < 8; ++j) b[j] = f2bf(wq * bv[j]);
#pragma unroll
    for (int i = 0; i < 4; ++i) {
      v8s a = A[(size_t)((mtB + i) * 16 + ks) * 64 + lane];
      acc[i] = __builtin_amdgcn_mfma_f32_16x16x32_bf16(a, b, acc[i], 0, 0, 0);
    }
    if (ks < 15) {
#pragma unroll
      for (int j = 0; j < 8; ++j) bv[j] = bn[j];
    }
  }
  int quad = lane >> 4, cn = nt * 16 + (lane & 15);
#pragma unroll
  for (int i = 0; i < 4; ++i) {
    int mt = mtB + i;
#pragma unroll
    for (int r = 0; r < 4; ++r) {
      int mp = mt * 16 + quad * 4 + r;
      float v = acc[i][r];
      if (mp < 256) ws[OFF_FRE + ((size_t)mp * 256 + t) * 32 + cn] = v;
      else          ws[OFF_FIM + ((size_t)(mp - 256) * 256 + t) * 32 + cn] = v;
    }
  }
}

// ---------------- forward Legendre MFMA (prefetched inline B): flm[m][l][c] fp32 ----------------
// grid 256, block 1024: wave = mt (1 tile each) -> 16 waves/CU
__global__ __launch_bounds__(1024) void k_legfwd(float* ws) {
  int m = blockIdx.x;
  int tid = threadIdx.x, mt = tid >> 6, lane = tid & 63;
  const v8s* A = (const v8s*)(ws + OFF_PA) + (size_t)m * 8192;
  int cl = lane & 15, tB = (lane >> 4) << 3;
  int quad = lane >> 4;
  v4f acc[4];
#pragma unroll
  for (int n = 0; n < 4; ++n) acc[n] = (v4f){0.f, 0.f, 0.f, 0.f};
  bool sk = (mt * 16 + 15) < m;
  if (!sk) {
    const float* Fb[4];
#pragma unroll
    for (int n = 0; n < 4; ++n) {
      int cp = n * 16 + cl;
      Fb[n] = ws + (cp < 32 ? OFF_FRE : OFF_FIM) + (size_t)m * 8192 + (size_t)tB * 32 + (cp & 31);
    }
    float bv[4][8];
#pragma unroll
    for (int n = 0; n < 4; ++n)
#pragma unroll
      for (int j = 0; j < 8; ++j) bv[n][j] = Fb[n][(size_t)j * 32];
    for (int ks = 0; ks < 8; ++ks) {
      float bn[4][8];
      if (ks < 7) {
#pragma unroll
        for (int n = 0; n < 4; ++n)
#pragma unroll
          for (int j = 0; j < 8; ++j) bn[n][j] = Fb[n][(size_t)((ks + 1) * 32 + j) * 32];
      }
      v8s a = A[(size_t)mt * 512 + ks * 64 + lane];
#pragma unroll
      for (int n = 0; n < 4; ++n) {
        v8s b;
#pragma unroll
        for (int j = 0; j < 8; ++j) b[j] = f2bf(bv[n][j]);
        acc[n] = __builtin_amdgcn_mfma_f32_16x16x32_bf16(a, b, acc[n], 0, 0, 0);
      }
      if (ks < 7) {
#pragma unroll
        for (int n = 0; n < 4; ++n)
#pragma unroll
          for (int j = 0; j < 8; ++j) bv[n][j] = bn[n][j];
      }
    }
  }
#pragma unroll
  for (int n = 0; n < 4; ++n) {
    int cp = n * 16 + cl;
    float* dst = ws + ((cp >= 32) ? OFF_SFIM : OFF_SFRE) + (size_t)m * 8192 + (cp & 31);
#pragma unroll
    for (int r = 0; r < 4; ++r) {
      int l = mt * 16 + quad * 4 + r;
      dst[(size_t)l * 32] = sk ? 0.f : acc[n][r];
    }
  }
}

// ---------------- conv (inline resize + inline weight premult) -> fp32 C[j][l][c] ----------------
__global__ __launch_bounds__(256) void k_conv(const float* w_real, const float* w_imag, float* ws) {
  // grid (4 jq, 128 l) x 256
  int jq = blockIdx.x, l = blockIdx.y;
  int tid = threadIdx.x;
  int jl = tid >> 5, o = tid & 31;
  __shared__ __align__(16) float wr[32 * 36];
  __shared__ __align__(16) float wi[32 * 36];
  __shared__ __align__(16) float fr[8 * 32];
  __shared__ __align__(16) float fi[8 * 32];
  {
    int oo = tid >> 3, i4 = (tid & 7) * 4;
    float tcr = ws[OFF_TC + l], tci = ws[OFF_TC + 128 + l];
#pragma unroll
    for (int q = 0; q < 4; ++q) {
      int i = i4 + q;
      float a = w_real[(size_t)l * 1024 + i * 32 + oo];
      float b = w_imag[(size_t)l * 1024 + i * 32 + oo];
      wr[oo * 36 + i] = tcr * a - tci * b;
      wi[oo * 36 + i] = tcr * b + tci * a;
    }
  }
  const float* SFRE = ws + OFF_SFRE;
  const float* SFIM = ws + OFF_SFIM;
  const float* WMW = ws + OFF_WMW;
  const int* WMI = (const int*)(ws + OFF_WMI);
  float wl[4]; int liv[4];
#pragma unroll
  for (int a = 0; a < 4; ++a) {
    wl[a] = ws[OFF_WLW + l * 4 + a];
    liv[a] = ((const int*)(ws + OFF_WLI))[l * 4 + a];
  }
  for (int ji = 0; ji < 8; ++ji) {
    int j = jq * 64 + ji * 8 + jl;
    int jp = (j < 255) ? j : 254;
    float accr = 0.f, acci = 0.f;
    for (int b = 0; b < 6; ++b) {
      float wm = WMW[jp * 6 + b];
      int jm = WMI[jp * 6 + b];
      bool mneg = (jm < 255);
      int mm = mneg ? (255 - jm) : (jm - 255);
      float fre_f = (mneg && (mm & 1)) ? -1.f : 1.f;
      float fim_f = mneg ? -fre_f : 1.f;
#pragma unroll
      for (int a = 0; a < 4; ++a) {
        float w = wm * wl[a];
        size_t base = ((size_t)mm * 256 + liv[a]) * 32 + o;
        accr = fmaf(w * fre_f, SFRE[base], accr);
        acci = fmaf(w * fim_f, SFIM[base], acci);
      }
    }
    __syncthreads();
    fr[jl * 32 + o] = accr;
    fi[jl * 32 + o] = acci;
    __syncthreads();
    float sr = 0.f, si = 0.f;
#pragma unroll
    for (int i0 = 0; i0 < 32; i0 += 4) {
      float4 f_r = *(const float4*)(fr + jl * 32 + i0);
      float4 f_i = *(const float4*)(fi + jl * 32 + i0);
      float4 w_r = *(const float4*)(wr + o * 36 + i0);
      float4 w_i = *(const float4*)(wi + o * 36 + i0);
      sr += f_r.x * w_r.x - f_i.x * w_i.x;  si += f_r.x * w_i.x + f_i.x * w_r.x;
      sr += f_r.y * w_r.y - f_i.y * w_i.y;  si += f_r.y * w_i.y + f_i.y * w_r.y;
      sr += f_r.z * w_r.z - f_i.z * w_i.z;  si += f_r.z * w_i.z + f_i.z * w_r.z;
      sr += f_r.w * w_r.w - f_i.w * w_i.w;  si += f_r.w * w_i.w + f_i.w * w_r.w;
    }
    if (j < 255) {
      float s = (j < 127 && ((127 - j) & 1)) ? -1.f : 1.f;   // (-1)^|m| for negative m
      ws[OFF_CRE + ((size_t)j * 128 + l) * 32 + o] = s * sr;
      ws[OFF_CIM + ((size_t)j * 128 + l) * 32 + o] = s * si;
    }
  }
}

// ---------------- inverse Legendre MFMA (prefetched inline B) -> fp32 G[t][j][c] ----------------
// grid 255, block 1024: wave = mt (1 tile each) -> 16 waves/CU
__global__ __launch_bounds__(1024) void k_gemm_linv(float* ws) {
  int j = blockIdx.x;
  int d = j - 127; int mm = (d < 0) ? -d : d;
  int tid = threadIdx.x, mt = tid >> 6, lane = tid & 63;
  const v8s* A = (const v8s*)(ws + OFF_PT) + (size_t)mm * 8192;
  int cl = lane & 15, lB = (lane >> 4) << 3;
  int quad = lane >> 4;
  v4f acc[4];
#pragma unroll
  for (int n = 0; n < 4; ++n) acc[n] = (v4f){0.f, 0.f, 0.f, 0.f};
  int ks0 = mm >> 5;
  const float* Cb[4];
#pragma unroll
  for (int n = 0; n < 4; ++n) {
    int cp = n * 16 + cl;
    Cb[n] = ws + (cp < 32 ? OFF_CRE : OFF_CIM) + ((size_t)j * 128 + lB) * 32 + (cp & 31);
  }
  float bv[4][8];
#pragma unroll
  for (int n = 0; n < 4; ++n)
#pragma unroll
    for (int j8 = 0; j8 < 8; ++j8) bv[n][j8] = Cb[n][(size_t)(ks0 * 32 + j8) * 32];
  for (int ks = ks0; ks < 4; ++ks) {   // l<128 only (padded flm zero above)
    float bn[4][8];
    if (ks < 3) {
#pragma unroll
      for (int n = 0; n < 4; ++n)
#pragma unroll
        for (int j8 = 0; j8 < 8; ++j8) bn[n][j8] = Cb[n][(size_t)((ks + 1) * 32 + j8) * 32];
    }
    v8s a = A[(size_t)mt * 512 + ks * 64 + lane];
#pragma unroll
    for (int n = 0; n < 4; ++n) {
      v8s b;
#pragma unroll
      for (int j8 = 0; j8 < 8; ++j8) b[j8] = f2bf(bv[n][j8]);
      acc[n] = __builtin_amdgcn_mfma_f32_16x16x32_bf16(a, b, acc[n], 0, 0, 0);
    }
    if (ks < 3) {
#pragma unroll
      for (int n = 0; n < 4; ++n)
#pragma unroll
        for (int j8 = 0; j8 < 8; ++j8) bv[n][j8] = bn[n][j8];
    }
  }
#pragma unroll
  for (int n = 0; n < 4; ++n) {
    int cp = n * 16 + cl;
    float* dst = ws + ((cp >= 32) ? OFF_GIM : OFF_GRE) + (size_t)(cp & 31);
#pragma unroll
    for (int r = 0; r < 4; ++r) {
      int t = mt * 16 + quad * 4 + r;
      dst[((size_t)t * 255 + j) * 32] = acc[n][r];
    }
  }
}

// ---------------- inverse DFT MFMA GEMM (prefetched inline B) -> out ----------------
// grid (4, 256): nt = bx&1, mh = bx>>1; wave does 4 mt tiles -> 16 waves/CU
__global__ __launch_bounds__(256) void k_gemm_i(const float* ws, float* out) {
  int bx = blockIdx.x, t = blockIdx.y;
  int nt = bx & 1, mh = bx >> 1;
  int tid = threadIdx.x, wave = tid >> 6, lane = tid & 63;
  const v8s* A = (const v8s*)(ws + OFF_AI);
  const float* GRE = ws + OFF_GRE;
  const float* GIM = ws + OFF_GIM;
  int mtB = mh * 16 + wave * 4;
  int cn = nt * 16 + (lane & 15);
  int kB = (lane >> 4) << 3;
  v4f acc[4];
#pragma unroll
  for (int i = 0; i < 4; ++i) acc[i] = (v4f){0.f, 0.f, 0.f, 0.f};
  float bv[8];
#pragma unroll
  for (int j8 = 0; j8 < 8; ++j8) {
    int k = kB + j8;
    float v = 0.f;
    if (k < 255)      v = GRE[((size_t)t * 255 + k) * 32 + cn];
    else if (k < 510) v = GIM[((size_t)t * 255 + (k - 255)) * 32 + cn];
    bv[j8] = v;
  }
  for (int ks = 0; ks < 16; ++ks) {
    float bn[8];
    if (ks < 15) {
      int k0 = (ks + 1) * 32 + kB;
#pragma unroll
      for (int j8 = 0; j8 < 8; ++j8) {
        int k = k0 + j8;
        float v = 0.f;
        if (k < 255)      v = GRE[((size_t)t * 255 + k) * 32 + cn];
        else if (k < 510) v = GIM[((size_t)t * 255 + (k - 255)) * 32 + cn];
        bn[j8] = v;
      }
    }
    v8s b;
#pragma unroll
    for (int j8 = 0; j8 < 8; ++j8) b[j8] = f2bf(bv[j8]);
#pragma unroll
    for (int i = 0; i < 4; ++i) {
      v8s a = A[(size_t)((mtB + i) * 16 + ks) * 64 + lane];
      acc[i] = __builtin_amdgcn_mfma_f32_16x16x32_bf16(a, b, acc[i], 0, 0, 0);
    }
    if (ks < 15) {
#pragma unroll
      for (int j8 = 0; j8 < 8; ++j8) bv[j8] = bn[j8];
    }
  }
  int quad = lane >> 4;
#pragma unroll
  for (int i = 0; i < 4; ++i) {
    int mt = mtB + i;
#pragma unroll
    for (int r = 0; r < 4; ++r) {
      int phi = mt * 16 + quad * 4 + r;
      if (phi < 511) out[((size_t)t * 511 + phi) * 32 + cn] = acc[i][r];
    }
  }
}

// ---------------- launch ----------------
extern "C" void kernel_launch(void* const* d_in, const int* in_sizes, int n_in,
                              void* d_out, int out_size, void* d_ws, size_t ws_size,
                              hipStream_t stream) {
  const float* x = (const float*)d_in[0];
  const float* t_emb = (const float*)d_in[1];
  const float* w_real = (const float*)d_in[2];
  const float* w_imag = (const float*)d_in[3];
  const float* w_tr = (const float*)d_in[4];
  const float* b_tr = (const float*)d_in[5];
  const float* w_ti = (const float*)d_in[6];
  const float* b_ti = (const float*)d_in[7];
  float* ws = (float*)d_ws;
  float* out = (float*)d_out;
  (void)in_sizes; (void)n_in; (void)out_size; (void)ws_size; // needs ~94 MB workspace

  hipLaunchKernelGGL(k_prep, dim3(2049), dim3(256), 0, stream,
                     t_emb, w_tr, b_tr, w_ti, b_ti, ws);
  hipLaunchKernelGGL(k_legendre, dim3(256), dim3(256), 0, stream, ws);
  hipLaunchKernelGGL(k_gemm_f, dim3(4, 256), dim3(256), 0, stream, x, ws);
  hipLaunchKernelGGL(k_legfwd, dim3(256), dim3(1024), 0, stream, ws);
  hipLaunchKernelGGL(k_conv, dim3(4, 128), dim3(256), 0, stream, w_real, w_imag, ws);
  hipLaunchKernelGGL(k_gemm_linv, dim3(255), dim3(1024), 0, stream, ws);
  hipLaunchKernelGGL(k_gemm_i, dim3(4, 256), dim3(256), 0, stream, ws, out);
}

// Round 11
// 198.073 us; speedup vs baseline: 1.3211x; 1.1267x over previous
//
#include <hip/hip_runtime.h>
#include <math.h>

#define PI_D 3.14159265358979323846

typedef short v8s __attribute__((ext_vector_type(8)));
typedef float v4f __attribute__((ext_vector_type(4)));

// ---------------- workspace layout (float offsets), total 23327232 floats = 93.3 MB ----------------
constexpr size_t OFF_PA   = 0;                   // legfwd A-frags bf16: per m, A[l][t]  (256 slices, 32 MB)
constexpr size_t OFF_PT   = 8388608;             // leginv A-frags bf16: per m<128, A[t][l] (16 MB)
constexpr size_t OFF_SFRE = 12582912;            // flm re [m][l][c] fp32 (8.4 MB)
constexpr size_t OFF_SFIM = 14680064;            // flm im
constexpr size_t OFF_FRE  = 16777216;            // fwd-DFT out fp32 F[m][t][c] (8.4 MB)
constexpr size_t OFF_FIM  = 18874368;
constexpr size_t OFF_CRE  = 20971520;            // conv out fp32 [j][l][c] (4.2 MB)
constexpr size_t OFF_CIM  = 22016000;
constexpr size_t OFF_AF   = 23060480;            // fwd DFT A-frags bf16 (512 KB)
constexpr size_t OFF_AI   = 23191552;            // inv DFT A-frags bf16 (512 KB)
constexpr size_t OFF_WQ   = 23322624;            // 256 quadrature weights
constexpr size_t OFF_TC   = 23322880;            // 256 (t_cplx re|im)
constexpr size_t OFF_WLW  = 23323136;            // 128*4 l-resize weights
constexpr size_t OFF_WLI  = 23323648;            // 128*4 l-resize indices (int)
constexpr size_t OFF_WMW  = 23324160;            // 255*6 m-resize weights
constexpr size_t OFF_WMI  = 23325696;            // 255*6 m-resize indices (int)
// overlays (lifetimes disjoint):
constexpr size_t OFF_GRE  = OFF_FRE;             // G fp32 [t][j][c] (F dead after legfwd)
constexpr size_t OFF_GIM  = OFF_FIM;

__device__ __forceinline__ short f2bf(float f) {   // RTNE float->bf16 bits
  unsigned u = __float_as_uint(f);
  unsigned r = (u + 0x7FFFu + ((u >> 16) & 1u)) >> 16;
  return (short)r;
}

// ================= phase bodies =================

__device__ void phase_prep(const float* t_emb, const float* w_tr, const float* b_tr,
                           const float* w_ti, const float* b_ti, float* ws, int g0, int tid) {
  if (g0 < 2048) {
    int g = g0 * 256 + tid;
    bool inv = (g >= 262144);
    int gid = inv ? g - 262144 : g;
    int j = gid & 7, lane = (gid >> 3) & 63, ks = (gid >> 9) & 15, mt = gid >> 13;
    int m = mt * 16 + (lane & 15);
    int k = ks * 32 + ((lane >> 4) << 3) + j;
    float v = 0.f;
    if (!inv) {
      if (k < 511) {
        int mm = (m < 256) ? m : m - 256;
        int kk = (mm * k) % 511;
        float ang = (float)(2.0 * PI_D / 511.0) * (float)kk;
        float s, c; __sincosf(ang, &s, &c);
        v = (m < 256) ? c : -s;
      }
      ((short*)(ws + OFF_AF))[gid] = f2bf(v);
    } else {
      if (m < 511 && k < 510) {
        int jj = (k < 255) ? k : k - 255;
        int jm = jj - 127;
        int kk = ((jm * m) % 511 + 511) % 511;
        float ang = (float)(2.0 * PI_D / 511.0) * (float)kk;
        float s, c; __sincosf(ang, &s, &c);
        v = (k < 255) ? c : -s;
      }
      ((short*)(ws + OFF_AI))[gid] = f2bf(v);
    }
    return;
  }
  // setup unit (g0 == 2048)
  if (tid < 256) {
    double theta = PI_D * (2.0 * tid + 1.0) / 511.0;
    double dang = 2.0 * PI_D / 511.0;
    ws[OFF_WQ + tid] = (float)(sin(theta) * dang * dang);
  }
  {
    int h = tid >> 7, o = tid & 127;
    const float* W = h ? w_ti : w_tr;
    float s = h ? b_ti[o] : b_tr[o];
    for (int T = 0; T < 256; ++T) s += t_emb[T] * W[T * 128 + o];
    ws[OFF_TC + h * 128 + o] = s;
  }
  if (tid < 128) {
    double sf = 2.0 * tid + 0.5;
    double wv[4]; int iv[4]; double wsum = 0.0;
    for (int a = 0; a < 4; ++a) {
      int t = 2 * tid - 1 + a;
      double r = 1.0 - fabs(sf - (double)t) * 0.5;
      bool valid = (t >= 0 && t < 256 && r > 0.0);
      wv[a] = valid ? r : 0.0; iv[a] = valid ? t : 0;
      wsum += wv[a];
    }
    for (int a = 0; a < 4; ++a) {
      ws[OFF_WLW + tid * 4 + a] = (float)(wv[a] / wsum);
      ((int*)(ws + OFF_WLI))[tid * 4 + a] = iv[a];
    }
  }
  if (tid < 255) {
    double inv2 = 511.0 / 255.0;
    double sf = (tid + 0.5) * inv2 - 0.5;
    int t0 = (int)floor(sf) - 2;
    double wv[6]; int iv[6]; double wsum = 0.0;
    for (int b = 0; b < 6; ++b) {
      int t = t0 + b;
      double r = 1.0 - fabs(sf - (double)t) * (255.0 / 511.0);
      bool valid = (t >= 0 && t < 511 && r > 0.0);
      wv[b] = valid ? r : 0.0; iv[b] = valid ? t : 0;
      wsum += wv[b];
    }
    for (int b = 0; b < 6; ++b) {
      ws[OFF_WMW + tid * 6 + b] = (float)(wv[b] / wsum);
      ((int*)(ws + OFF_WMI))[tid * 6 + b] = iv[b];
    }
  }
}

// smem layout (32768 B): cA[256]d | cB[256]d | cS[256]d | tile 16x280 s | tileT 256x34 s
__device__ void phase_legendre(float* ws, char* smem, int m, int t) {
  double* cA = (double*)smem;
  double* cB = cA + 256;
  double* cS = cB + 256;
  short* tile = (short*)(smem + 6144);
  short* tileT = (short*)(smem + 6144 + 8960);
  {
    int l = t;
    if (l >= 1) cS[l] = -sqrt((2.0 * l + 1.0) / (2.0 * l));
    if (l >= m + 2) {
      double ll = l, mm = m;
      double den = ll * ll - mm * mm;
      cA[l] = sqrt((4.0 * ll * ll - 1.0) / den);
      cB[l] = sqrt((2.0 * ll + 1.0) * (ll - 1.0 - mm) * (ll - 1.0 + mm) /
                   ((2.0 * ll - 3.0) * den));
    }
  }
  __syncthreads();
  bool wantPT = (m < 128);
  short* PAp = (short*)(ws + OFF_PA) + (size_t)m * 65536;
  short* PTp = (short*)(ws + OFF_PT) + (size_t)m * 65536;
  double theta = PI_D * (2.0 * t + 1.0) / 511.0;
  double ct = cos(theta), st = sin(theta);
  double p0 = sqrt(1.0 / (4.0 * PI_D));
  for (int k = 1; k <= m; ++k) p0 *= cS[k] * st;
  double pm1 = 0.0, pcur = 0.0;
  for (int lt = 0; lt < 16; ++lt) {
    for (int li = 0; li < 16; ++li) {
      int l = lt * 16 + li;
      float v;
      if (l < m) v = 0.f;
      else if (l == m) { pcur = p0; v = (float)pcur; }
      else if (l == m + 1) { pm1 = pcur; pcur = sqrt(2.0 * m + 3.0) * ct * pm1; v = (float)pcur; }
      else { double p2 = cA[l] * ct * pcur - cB[l] * pm1; pm1 = pcur; pcur = p2; v = (float)p2; }
      short bv = f2bf(v);
      tile[li * 280 + t] = bv;
      if (wantPT) tileT[t * 34 + li] = bv;
    }
    __syncthreads();
#pragma unroll
    for (int pass = 0; pass < 2; ++pass) {
      int ch = pass * 256 + t;
      int li = ch & 15, T0 = ch >> 4;
      size_t dst = (size_t)lt * 4096 + (size_t)(T0 >> 2) * 512 + (size_t)((T0 & 3) * 16 + li) * 8;
      *(v8s*)(PAp + dst) = *(const v8s*)(tile + li * 280 + T0 * 8);
    }
    if (wantPT) {
#pragma unroll
      for (int pass = 0; pass < 2; ++pass) {
        int ch = pass * 256 + t;
        int tt = ch >> 1, li0 = (ch & 1) * 8;
        size_t dst = (size_t)(tt >> 4) * 4096 + (size_t)(lt >> 1) * 512 +
                     (size_t)(((lt & 1) * 2 + (li0 >> 3)) * 16 + (tt & 15)) * 8;
        const int* src = (const int*)(tileT + tt * 34 + li0);
        int* d = (int*)(PTp + dst);
        d[0] = src[0]; d[1] = src[1]; d[2] = src[2]; d[3] = src[3];
      }
    }
    __syncthreads();
  }
}

// uid in [0,1024): nt = uid&1, mh = (uid>>1)&1, t = uid>>2; A+B double-buffered
__device__ void phase_gemm_f(const float* x, float* ws, int uid, int tid) {
  int nt = uid & 1, mh = (uid >> 1) & 1, t = uid >> 2;
  int wave = tid >> 6, lane = tid & 63;
  const v8s* A = (const v8s*)(ws + OFF_AF);
  float wq = ws[OFF_WQ + t];
  const float* xb = x + (size_t)t * 511 * 32 + nt * 16 + (lane & 15);
  int phiB = (lane >> 4) << 3;
  int mtB = mh * 16 + wave * 4;
  v4f acc[4];
#pragma unroll
  for (int i = 0; i < 4; ++i) acc[i] = (v4f){0.f, 0.f, 0.f, 0.f};
  float bv[8];
  v8s a_cur[4], a_nxt[4];
#pragma unroll
  for (int j = 0; j < 8; ++j) {
    int phi = phiB + j;
    bv[j] = (phi < 511) ? xb[(size_t)phi * 32] : 0.f;
  }
#pragma unroll
  for (int i = 0; i < 4; ++i) a_cur[i] = A[(size_t)((mtB + i) * 16 + 0) * 64 + lane];
  for (int ks = 0; ks < 16; ++ks) {
    float bn[8];
    if (ks < 15) {
      int phi0 = (ks + 1) * 32 + phiB;
#pragma unroll
      for (int j = 0; j < 8; ++j) {
        int phi = phi0 + j;
        bn[j] = (phi < 511) ? xb[(size_t)phi * 32] : 0.f;
      }
#pragma unroll
      for (int i = 0; i < 4; ++i)
        a_nxt[i] = A[(size_t)((mtB + i) * 16 + ks + 1) * 64 + lane];
    }
    v8s b;
#pragma unroll
    for (int j = 0; j < 8; ++j) b[j] = f2bf(wq * bv[j]);
#pragma unroll
    for (int i = 0; i < 4; ++i)
      acc[i] = __builtin_amdgcn_mfma_f32_16x16x32_bf16(a_cur[i], b, acc[i], 0, 0, 0);
    if (ks < 15) {
#pragma unroll
      for (int j = 0; j < 8; ++j) bv[j] = bn[j];
#pragma unroll
      for (int i = 0; i < 4; ++i) a_cur[i] = a_nxt[i];
    }
  }
  int quad = lane >> 4, cn = nt * 16 + (lane & 15);
#pragma unroll
  for (int i = 0; i < 4; ++i) {
    int mt = mtB + i;
#pragma unroll
    for (int r = 0; r < 4; ++r) {
      int mp = mt * 16 + quad * 4 + r;
      float v = acc[i][r];
      if (mp < 256) ws[OFF_FRE + ((size_t)mp * 256 + t) * 32 + cn] = v;
      else          ws[OFF_FIM + ((size_t)(mp - 256) * 256 + t) * 32 + cn] = v;
    }
  }
}

// uid in [0,1024): m = uid>>2, mt = (uid&3)*4 + wave; A+B double-buffered
__device__ void phase_legfwd(float* ws, int uid, int tid) {
  int m = uid >> 2;
  int mt = (uid & 3) * 4 + (tid >> 6), lane = tid & 63;
  const v8s* A = (const v8s*)(ws + OFF_PA) + (size_t)m * 8192;
  int cl = lane & 15, tB = (lane >> 4) << 3;
  int quad = lane >> 4;
  v4f acc[4];
#pragma unroll
  for (int n = 0; n < 4; ++n) acc[n] = (v4f){0.f, 0.f, 0.f, 0.f};
  bool sk = (mt * 16 + 15) < m;
  if (!sk) {
    const float* Fb[4];
#pragma unroll
    for (int n = 0; n < 4; ++n) {
      int cp = n * 16 + cl;
      Fb[n] = ws + (cp < 32 ? OFF_FRE : OFF_FIM) + (size_t)m * 8192 + (size_t)tB * 32 + (cp & 31);
    }
    float bv[4][8];
    v8s a_cur = A[(size_t)mt * 512 + lane];
#pragma unroll
    for (int n = 0; n < 4; ++n)
#pragma unroll
      for (int j = 0; j < 8; ++j) bv[n][j] = Fb[n][(size_t)j * 32];
    for (int ks = 0; ks < 8; ++ks) {
      float bn[4][8];
      v8s a_nxt;
      if (ks < 7) {
#pragma unroll
        for (int n = 0; n < 4; ++n)
#pragma unroll
          for (int j = 0; j < 8; ++j) bn[n][j] = Fb[n][(size_t)((ks + 1) * 32 + j) * 32];
        a_nxt = A[(size_t)mt * 512 + (ks + 1) * 64 + lane];
      }
#pragma unroll
      for (int n = 0; n < 4; ++n) {
        v8s b;
#pragma unroll
        for (int j = 0; j < 8; ++j) b[j] = f2bf(bv[n][j]);
        acc[n] = __builtin_amdgcn_mfma_f32_16x16x32_bf16(a_cur, b, acc[n], 0, 0, 0);
      }
      if (ks < 7) {
#pragma unroll
        for (int n = 0; n < 4; ++n)
#pragma unroll
          for (int j = 0; j < 8; ++j) bv[n][j] = bn[n][j];
        a_cur = a_nxt;
      }
    }
  }
#pragma unroll
  for (int n = 0; n < 4; ++n) {
    int cp = n * 16 + cl;
    float* dst = ws + ((cp >= 32) ? OFF_SFIM : OFF_SFRE) + (size_t)m * 8192 + (cp & 31);
#pragma unroll
    for (int r = 0; r < 4; ++r) {
      int l = mt * 16 + quad * 4 + r;
      dst[(size_t)l * 32] = sk ? 0.f : acc[n][r];
    }
  }
}

// smem layout: wr 32x36 f | wi 32x36 f | fr 8x32 f | fi 8x32 f  (11264 B)
__device__ void phase_conv(const float* w_real, const float* w_imag, float* ws, char* smem,
                           int uid, int tid) {
  int l = uid >> 3, jq8 = uid & 7;
  int jl = tid >> 5, o = tid & 31;
  float* wr = (float*)smem;
  float* wi = wr + 32 * 36;
  float* fr = wi + 32 * 36;
  float* fi = fr + 8 * 32;
  {
    int oo = tid >> 3, i4 = (tid & 7) * 4;
    float tcr = ws[OFF_TC + l], tci = ws[OFF_TC + 128 + l];
#pragma unroll
    for (int q = 0; q < 4; ++q) {
      int i = i4 + q;
      float a = w_real[(size_t)l * 1024 + i * 32 + oo];
      float b = w_imag[(size_t)l * 1024 + i * 32 + oo];
      wr[oo * 36 + i] = tcr * a - tci * b;
      wi[oo * 36 + i] = tcr * b + tci * a;
    }
  }
  const float* SFRE = ws + OFF_SFRE;
  const float* SFIM = ws + OFF_SFIM;
  const float* WMW = ws + OFF_WMW;
  const int* WMI = (const int*)(ws + OFF_WMI);
  float wl[4]; int liv[4];
#pragma unroll
  for (int a = 0; a < 4; ++a) {
    wl[a] = ws[OFF_WLW + l * 4 + a];
    liv[a] = ((const int*)(ws + OFF_WLI))[l * 4 + a];
  }
  for (int ji = 0; ji < 4; ++ji) {
    int j = jq8 * 32 + ji * 8 + jl;
    int jp = (j < 255) ? j : 254;
    float accr = 0.f, acci = 0.f;
    for (int b = 0; b < 6; ++b) {
      float wm = WMW[jp * 6 + b];
      int jm = WMI[jp * 6 + b];
      bool mneg = (jm < 255);
      int mm = mneg ? (255 - jm) : (jm - 255);
      float fre_f = (mneg && (mm & 1)) ? -1.f : 1.f;
      float fim_f = mneg ? -fre_f : 1.f;
#pragma unroll
      for (int a = 0; a < 4; ++a) {
        float w = wm * wl[a];
        size_t base = ((size_t)mm * 256 + liv[a]) * 32 + o;
        accr = fmaf(w * fre_f, SFRE[base], accr);
        acci = fmaf(w * fim_f, SFIM[base], acci);
      }
    }
    __syncthreads();
    fr[jl * 32 + o] = accr;
    fi[jl * 32 + o] = acci;
    __syncthreads();
    float sr = 0.f, si = 0.f;
#pragma unroll
    for (int i0 = 0; i0 < 32; i0 += 4) {
      float4 f_r = *(const float4*)(fr + jl * 32 + i0);
      float4 f_i = *(const float4*)(fi + jl * 32 + i0);
      float4 w_r = *(const float4*)(wr + o * 36 + i0);
      float4 w_i = *(const float4*)(wi + o * 36 + i0);
      sr += f_r.x * w_r.x - f_i.x * w_i.x;  si += f_r.x * w_i.x + f_i.x * w_r.x;
      sr += f_r.y * w_r.y - f_i.y * w_i.y;  si += f_r.y * w_i.y + f_i.y * w_r.y;
      sr += f_r.z * w_r.z - f_i.z * w_i.z;  si += f_r.z * w_i.z + f_i.z * w_r.z;
      sr += f_r.w * w_r.w - f_i.w * w_i.w;  si += f_r.w * w_i.w + f_i.w * w_r.w;
    }
    if (j < 255) {
      float s = (j < 127 && ((127 - j) & 1)) ? -1.f : 1.f;   // (-1)^|m| for negative m
      ws[OFF_CRE + ((size_t)j * 128 + l) * 32 + o] = s * sr;
      ws[OFF_CIM + ((size_t)j * 128 + l) * 32 + o] = s * si;
    }
  }
}

// uid in [0,1020): j = uid>>2, mt = (uid&3)*4 + wave; A+B double-buffered
__device__ void phase_linv(float* ws, int uid, int tid) {
  int j = uid >> 2;
  int d = j - 127; int mm = (d < 0) ? -d : d;
  int mt = (uid & 3) * 4 + (tid >> 6), lane = tid & 63;
  const v8s* A = (const v8s*)(ws + OFF_PT) + (size_t)mm * 8192;
  int cl = lane & 15, lB = (lane >> 4) << 3;
  int quad = lane >> 4;
  v4f acc[4];
#pragma unroll
  for (int n = 0; n < 4; ++n) acc[n] = (v4f){0.f, 0.f, 0.f, 0.f};
  int ks0 = mm >> 5;
  const float* Cb[4];
#pragma unroll
  for (int n = 0; n < 4; ++n) {
    int cp = n * 16 + cl;
    Cb[n] = ws + (cp < 32 ? OFF_CRE : OFF_CIM) + ((size_t)j * 128 + lB) * 32 + (cp & 31);
  }
  float bv[4][8];
  v8s a_cur = A[(size_t)mt * 512 + ks0 * 64 + lane];
#pragma unroll
  for (int n = 0; n < 4; ++n)
#pragma unroll
    for (int j8 = 0; j8 < 8; ++j8) bv[n][j8] = Cb[n][(size_t)(ks0 * 32 + j8) * 32];
  for (int ks = ks0; ks < 4; ++ks) {   // l<128 only (padded flm zero above)
    float bn[4][8];
    v8s a_nxt;
    if (ks < 3) {
#pragma unroll
      for (int n = 0; n < 4; ++n)
#pragma unroll
        for (int j8 = 0; j8 < 8; ++j8) bn[n][j8] = Cb[n][(size_t)((ks + 1) * 32 + j8) * 32];
      a_nxt = A[(size_t)mt * 512 + (ks + 1) * 64 + lane];
    }
#pragma unroll
    for (int n = 0; n < 4; ++n) {
      v8s b;
#pragma unroll
      for (int j8 = 0; j8 < 8; ++j8) b[j8] = f2bf(bv[n][j8]);
      acc[n] = __builtin_amdgcn_mfma_f32_16x16x32_bf16(a_cur, b, acc[n], 0, 0, 0);
    }
    if (ks < 3) {
#pragma unroll
      for (int n = 0; n < 4; ++n)
#pragma unroll
        for (int j8 = 0; j8 < 8; ++j8) bv[n][j8] = bn[n][j8];
      a_cur = a_nxt;
    }
  }
#pragma unroll
  for (int n = 0; n < 4; ++n) {
    int cp = n * 16 + cl;
    float* dst = ws + ((cp >= 32) ? OFF_GIM : OFF_GRE) + (size_t)(cp & 31);
#pragma unroll
    for (int r = 0; r < 4; ++r) {
      int t = mt * 16 + quad * 4 + r;
      dst[((size_t)t * 255 + j) * 32] = acc[n][r];
    }
  }
}

// uid in [0,1024): nt = uid&1, mh = (uid>>1)&1, t = uid>>2; A+B double-buffered
__device__ void phase_gemm_i(const float* ws, float* out, int uid, int tid) {
  int nt = uid & 1, mh = (uid >> 1) & 1, t = uid >> 2;
  int wave = tid >> 6, lane = tid & 63;
  const v8s* A = (const v8s*)(ws + OFF_AI);
  const float* GRE = ws + OFF_GRE;
  const float* GIM = ws + OFF_GIM;
  int mtB = mh * 16 + wave * 4;
  int cn = nt * 16 + (lane & 15);
  int kB = (lane >> 4) << 3;
  v4f acc[4];
#pragma unroll
  for (int i = 0; i < 4; ++i) acc[i] = (v4f){0.f, 0.f, 0.f, 0.f};
  float bv[8];
  v8s a_cur[4], a_nxt[4];
#pragma unroll
  for (int j8 = 0; j8 < 8; ++j8) {
    int k = kB + j8;
    float v = 0.f;
    if (k < 255)      v = GRE[((size_t)t * 255 + k) * 32 + cn];
    else if (k < 510) v = GIM[((size_t)t * 255 + (k - 255)) * 32 + cn];
    bv[j8] = v;
  }
#pragma unroll
  for (int i = 0; i < 4; ++i) a_cur[i] = A[(size_t)((mtB + i) * 16 + 0) * 64 + lane];
  for (int ks = 0; ks < 16; ++ks) {
    float bn[8];
    if (ks < 15) {
      int k0 = (ks + 1) * 32 + kB;
#pragma unroll
      for (int j8 = 0; j8 < 8; ++j8) {
        int k = k0 + j8;
        float v = 0.f;
        if (k < 255)      v = GRE[((size_t)t * 255 + k) * 32 + cn];
        else if (k < 510) v = GIM[((size_t)t * 255 + (k - 255)) * 32 + cn];
        bn[j8] = v;
      }
#pragma unroll
      for (int i = 0; i < 4; ++i)
        a_nxt[i] = A[(size_t)((mtB + i) * 16 + ks + 1) * 64 + lane];
    }
    v8s b;
#pragma unroll
    for (int j8 = 0; j8 < 8; ++j8) b[j8] = f2bf(bv[j8]);
#pragma unroll
    for (int i = 0; i < 4; ++i)
      acc[i] = __builtin_amdgcn_mfma_f32_16x16x32_bf16(a_cur[i], b, acc[i], 0, 0, 0);
    if (ks < 15) {
#pragma unroll
      for (int j8 = 0; j8 < 8; ++j8) bv[j8] = bn[j8];
#pragma unroll
      for (int i = 0; i < 4; ++i) a_cur[i] = a_nxt[i];
    }
  }
  int quad = lane >> 4;
#pragma unroll
  for (int i = 0; i < 4; ++i) {
    int mt = mtB + i;
#pragma unroll
    for (int r = 0; r < 4; ++r) {
      int phi = mt * 16 + quad * 4 + r;
      if (phi < 511) out[((size_t)t * 511 + phi) * 32 + cn] = acc[i][r];
    }
  }
}

// ================= kernels (plain launches only — NO cooperative launch, it breaks
// the harness's graph capture; confirmed R10) =================
__global__ __launch_bounds__(256) void k_prepleg(const float* t_emb, const float* w_tr,
                                                 const float* b_tr, const float* w_ti,
                                                 const float* b_ti, float* ws) {
  // blocks 0..2048: prep tables+setup; blocks 2049..2304: legendre m = bid-2049
  __shared__ __align__(16) char smem[32768];
  int bid = blockIdx.x;
  if (bid < 2049) phase_prep(t_emb, w_tr, b_tr, w_ti, b_ti, ws, bid, threadIdx.x);
  else phase_legendre(ws, smem, bid - 2049, threadIdx.x);
}
__global__ __launch_bounds__(256) void kw_gemm_f(const float* x, float* ws) {
  phase_gemm_f(x, ws, blockIdx.x, threadIdx.x);
}
__global__ __launch_bounds__(256) void kw_legfwd(float* ws) {
  phase_legfwd(ws, blockIdx.x, threadIdx.x);
}
__global__ __launch_bounds__(256) void kw_conv(const float* w_real, const float* w_imag, float* ws) {
  __shared__ __align__(16) char smem[32768];
  phase_conv(w_real, w_imag, ws, smem, blockIdx.x, threadIdx.x);
}
__global__ __launch_bounds__(256) void kw_linv(float* ws) {
  phase_linv(ws, blockIdx.x, threadIdx.x);
}
__global__ __launch_bounds__(256) void kw_gemm_i(const float* ws, float* out) {
  phase_gemm_i(ws, out, blockIdx.x, threadIdx.x);
}

// ---------------- launch ----------------
extern "C" void kernel_launch(void* const* d_in, const int* in_sizes, int n_in,
                              void* d_out, int out_size, void* d_ws, size_t ws_size,
                              hipStream_t stream) {
  const float* x = (const float*)d_in[0];
  const float* t_emb = (const float*)d_in[1];
  const float* w_real = (const float*)d_in[2];
  const float* w_imag = (const float*)d_in[3];
  const float* w_tr = (const float*)d_in[4];
  const float* b_tr = (const float*)d_in[5];
  const float* w_ti = (const float*)d_in[6];
  const float* b_ti = (const float*)d_in[7];
  float* ws = (float*)d_ws;
  float* out = (float*)d_out;
  (void)in_sizes; (void)n_in; (void)out_size; (void)ws_size; // needs ~94 MB workspace

  hipLaunchKernelGGL(k_prepleg, dim3(2305), dim3(256), 0, stream,
                     t_emb, w_tr, b_tr, w_ti, b_ti, ws);
  hipLaunchKernelGGL(kw_gemm_f, dim3(1024), dim3(256), 0, stream, x, ws);
  hipLaunchKernelGGL(kw_legfwd, dim3(1024), dim3(256), 0, stream, ws);
  hipLaunchKernelGGL(kw_conv, dim3(1024), dim3(256), 0, stream, w_real, w_imag, ws);
  hipLaunchKernelGGL(kw_linv, dim3(1020), dim3(256), 0, stream, ws);
  hipLaunchKernelGGL(kw_gemm_i, dim3(1024), dim3(256), 0, stream, ws, out);
}

// Round 12
// 188.293 us; speedup vs baseline: 1.3897x; 1.0519x over previous
//
#include <hip/hip_runtime.h>
#include <math.h>

#define PI_D 3.14159265358979323846

typedef short v8s __attribute__((ext_vector_type(8)));
typedef float v4f __attribute__((ext_vector_type(4)));

// ---------------- workspace layout (float offsets), total 23327232 floats = 93.3 MB ----------------
constexpr size_t OFF_PA   = 0;                   // legfwd A-frags bf16: per m, A[l][t]  (256 slices, 32 MB)
constexpr size_t OFF_PT   = 8388608;             // leginv A-frags bf16: per m<128, A[t][l] (16 MB)
constexpr size_t OFF_SFRE = 12582912;            // flm re [m][l][c] fp32 (8.4 MB)
constexpr size_t OFF_SFIM = 14680064;            // flm im
constexpr size_t OFF_FRE  = 16777216;            // fwd-DFT out fp32 F[m][t][c] (8.4 MB)
constexpr size_t OFF_FIM  = 18874368;
constexpr size_t OFF_CRE  = 20971520;            // conv out fp32 [j][l][c] (4.2 MB)
constexpr size_t OFF_CIM  = 22016000;
constexpr size_t OFF_AF   = 23060480;            // fwd DFT A-frags bf16 (512 KB)
constexpr size_t OFF_AI   = 23191552;            // inv DFT A-frags bf16 (512 KB)
constexpr size_t OFF_WQ   = 23322624;            // 256 quadrature weights
constexpr size_t OFF_TC   = 23322880;            // 256 (t_cplx re|im)
constexpr size_t OFF_WLW  = 23323136;            // 128*4 l-resize weights
constexpr size_t OFF_WLI  = 23323648;            // 128*4 l-resize indices (int)
constexpr size_t OFF_WMW  = 23324160;            // 255*6 m-resize weights
constexpr size_t OFF_WMI  = 23325696;            // 255*6 m-resize indices (int)
// overlays (lifetimes disjoint):
constexpr size_t OFF_GRE  = OFF_FRE;             // G fp32 [t][j][c] (F dead after legfwd)
constexpr size_t OFF_GIM  = OFF_FIM;

__device__ __forceinline__ short f2bf(float f) {   // RTNE float->bf16 bits
  unsigned u = __float_as_uint(f);
  unsigned r = (u + 0x7FFFu + ((u >> 16) & 1u)) >> 16;
  return (short)r;
}

// ================= phase bodies =================

__device__ void phase_prep(const float* t_emb, const float* w_tr, const float* b_tr,
                           const float* w_ti, const float* b_ti, float* ws, int g0, int tid) {
  if (g0 < 2048) {
    int g = g0 * 256 + tid;
    bool inv = (g >= 262144);
    int gid = inv ? g - 262144 : g;
    int j = gid & 7, lane = (gid >> 3) & 63, ks = (gid >> 9) & 15, mt = gid >> 13;
    int m = mt * 16 + (lane & 15);
    int k = ks * 32 + ((lane >> 4) << 3) + j;
    float v = 0.f;
    if (!inv) {
      if (k < 511) {
        int mm = (m < 256) ? m : m - 256;
        int kk = (mm * k) % 511;
        float ang = (float)(2.0 * PI_D / 511.0) * (float)kk;
        float s, c; __sincosf(ang, &s, &c);
        v = (m < 256) ? c : -s;
      }
      ((short*)(ws + OFF_AF))[gid] = f2bf(v);
    } else {
      if (m < 511 && k < 510) {
        int jj = (k < 255) ? k : k - 255;
        int jm = jj - 127;
        int kk = ((jm * m) % 511 + 511) % 511;
        float ang = (float)(2.0 * PI_D / 511.0) * (float)kk;
        float s, c; __sincosf(ang, &s, &c);
        v = (k < 255) ? c : -s;
      }
      ((short*)(ws + OFF_AI))[gid] = f2bf(v);
    }
    return;
  }
  // setup unit (g0 == 2048)
  if (tid < 256) {
    double theta = PI_D * (2.0 * tid + 1.0) / 511.0;
    double dang = 2.0 * PI_D / 511.0;
    ws[OFF_WQ + tid] = (float)(sin(theta) * dang * dang);
  }
  {
    int h = tid >> 7, o = tid & 127;
    const float* W = h ? w_ti : w_tr;
    float s = h ? b_ti[o] : b_tr[o];
    for (int T = 0; T < 256; ++T) s += t_emb[T] * W[T * 128 + o];
    ws[OFF_TC + h * 128 + o] = s;
  }
  if (tid < 128) {
    double sf = 2.0 * tid + 0.5;
    double wv[4]; int iv[4]; double wsum = 0.0;
    for (int a = 0; a < 4; ++a) {
      int t = 2 * tid - 1 + a;
      double r = 1.0 - fabs(sf - (double)t) * 0.5;
      bool valid = (t >= 0 && t < 256 && r > 0.0);
      wv[a] = valid ? r : 0.0; iv[a] = valid ? t : 0;
      wsum += wv[a];
    }
    for (int a = 0; a < 4; ++a) {
      ws[OFF_WLW + tid * 4 + a] = (float)(wv[a] / wsum);
      ((int*)(ws + OFF_WLI))[tid * 4 + a] = iv[a];
    }
  }
  if (tid < 255) {
    double inv2 = 511.0 / 255.0;
    double sf = (tid + 0.5) * inv2 - 0.5;
    int t0 = (int)floor(sf) - 2;
    double wv[6]; int iv[6]; double wsum = 0.0;
    for (int b = 0; b < 6; ++b) {
      int t = t0 + b;
      double r = 1.0 - fabs(sf - (double)t) * (255.0 / 511.0);
      bool valid = (t >= 0 && t < 511 && r > 0.0);
      wv[b] = valid ? r : 0.0; iv[b] = valid ? t : 0;
      wsum += wv[b];
    }
    for (int b = 0; b < 6; ++b) {
      ws[OFF_WMW + tid * 6 + b] = (float)(wv[b] / wsum);
      ((int*)(ws + OFF_WMI))[tid * 6 + b] = iv[b];
    }
  }
}

// smem layout (32768 B): cA[256]d | cB[256]d | cS[256]d | tile 16x280 s | tileT 256x34 s
__device__ void phase_legendre(float* ws, char* smem, int m, int t) {
  double* cA = (double*)smem;
  double* cB = cA + 256;
  double* cS = cB + 256;
  short* tile = (short*)(smem + 6144);
  short* tileT = (short*)(smem + 6144 + 8960);
  {
    int l = t;
    if (l >= 1) cS[l] = -sqrt((2.0 * l + 1.0) / (2.0 * l));
    if (l >= m + 2) {
      double ll = l, mm = m;
      double den = ll * ll - mm * mm;
      cA[l] = sqrt((4.0 * ll * ll - 1.0) / den);
      cB[l] = sqrt((2.0 * ll + 1.0) * (ll - 1.0 - mm) * (ll - 1.0 + mm) /
                   ((2.0 * ll - 3.0) * den));
    }
  }
  __syncthreads();
  bool wantPT = (m < 128);
  short* PAp = (short*)(ws + OFF_PA) + (size_t)m * 65536;
  short* PTp = (short*)(ws + OFF_PT) + (size_t)m * 65536;
  double theta = PI_D * (2.0 * t + 1.0) / 511.0;
  double ct = cos(theta), st = sin(theta);
  double p0 = sqrt(1.0 / (4.0 * PI_D));
  for (int k = 1; k <= m; ++k) p0 *= cS[k] * st;
  double pm1 = 0.0, pcur = 0.0;
  for (int lt = 0; lt < 16; ++lt) {
    for (int li = 0; li < 16; ++li) {
      int l = lt * 16 + li;
      float v;
      if (l < m) v = 0.f;
      else if (l == m) { pcur = p0; v = (float)pcur; }
      else if (l == m + 1) { pm1 = pcur; pcur = sqrt(2.0 * m + 3.0) * ct * pm1; v = (float)pcur; }
      else { double p2 = cA[l] * ct * pcur - cB[l] * pm1; pm1 = pcur; pcur = p2; v = (float)p2; }
      short bv = f2bf(v);
      tile[li * 280 + t] = bv;
      if (wantPT) tileT[t * 34 + li] = bv;
    }
    __syncthreads();
#pragma unroll
    for (int pass = 0; pass < 2; ++pass) {
      int ch = pass * 256 + t;
      int li = ch & 15, T0 = ch >> 4;
      size_t dst = (size_t)lt * 4096 + (size_t)(T0 >> 2) * 512 + (size_t)((T0 & 3) * 16 + li) * 8;
      *(v8s*)(PAp + dst) = *(const v8s*)(tile + li * 280 + T0 * 8);
    }
    if (wantPT) {
#pragma unroll
      for (int pass = 0; pass < 2; ++pass) {
        int ch = pass * 256 + t;
        int tt = ch >> 1, li0 = (ch & 1) * 8;
        size_t dst = (size_t)(tt >> 4) * 4096 + (size_t)(lt >> 1) * 512 +
                     (size_t)(((lt & 1) * 2 + (li0 >> 3)) * 16 + (tt & 15)) * 8;
        const int* src = (const int*)(tileT + tt * 34 + li0);
        int* d = (int*)(PTp + dst);
        d[0] = src[0]; d[1] = src[1]; d[2] = src[2]; d[3] = src[3];
      }
    }
    __syncthreads();
  }
}

// uid in [0,1024): nt = uid&1, mh = (uid>>1)&1, t = uid>>2
// B-panel shared across the block's 4 waves via double-buffered LDS (2x640 shorts).
__device__ void phase_gemm_f(const float* x, float* ws, short* lds, int uid, int tid) {
  int nt = uid & 1, mh = (uid >> 1) & 1, t = uid >> 2;
  int wave = tid >> 6, lane = tid & 63;
  const v8s* A = (const v8s*)(ws + OFF_AF);
  float wq = ws[OFF_WQ + t];
  const float* row = x + (size_t)t * 511 * 32 + nt * 16;
  int cl = lane & 15, quad = lane >> 4;
  int mtB = mh * 16 + wave * 4;
  int ck = tid >> 4, cc = tid & 15;   // coop: element tid -> (k=ck,c=cc); tid+256 -> (k=ck+16,c=cc)
  v4f acc[4];
#pragma unroll
  for (int i = 0; i < 4; ++i) acc[i] = (v4f){0.f, 0.f, 0.f, 0.f};
  v8s a_cur[4], a_nxt[4];
#pragma unroll
  for (int i = 0; i < 4; ++i) a_cur[i] = A[(size_t)((mtB + i) * 16 + 0) * 64 + lane];
  {
    float p0 = wq * row[(size_t)ck * 32 + cc];
    float p1 = wq * row[(size_t)(ck + 16) * 32 + cc];
    lds[cc * 40 + ck] = f2bf(p0);
    lds[cc * 40 + ck + 16] = f2bf(p1);
  }
  __syncthreads();
  for (int ks = 0; ks < 16; ++ks) {
    float n0 = 0.f, n1 = 0.f;
    if (ks < 15) {
      int ph0 = (ks + 1) * 32 + ck, ph1 = ph0 + 16;
      n0 = (ph0 < 511) ? wq * row[(size_t)ph0 * 32 + cc] : 0.f;
      n1 = (ph1 < 511) ? wq * row[(size_t)ph1 * 32 + cc] : 0.f;
#pragma unroll
      for (int i = 0; i < 4; ++i)
        a_nxt[i] = A[(size_t)((mtB + i) * 16 + ks + 1) * 64 + lane];
    }
    v8s b = *(const v8s*)(lds + (ks & 1) * 640 + cl * 40 + quad * 8);
#pragma unroll
    for (int i = 0; i < 4; ++i)
      acc[i] = __builtin_amdgcn_mfma_f32_16x16x32_bf16(a_cur[i], b, acc[i], 0, 0, 0);
    if (ks < 15) {
      short* nb = lds + ((ks + 1) & 1) * 640;
      nb[cc * 40 + ck] = f2bf(n0);
      nb[cc * 40 + ck + 16] = f2bf(n1);
#pragma unroll
      for (int i = 0; i < 4; ++i) a_cur[i] = a_nxt[i];
      __syncthreads();
    }
  }
  int cn = nt * 16 + cl;
#pragma unroll
  for (int i = 0; i < 4; ++i) {
    int mt = mtB + i;
#pragma unroll
    for (int r = 0; r < 4; ++r) {
      int mp = mt * 16 + quad * 4 + r;
      float v = acc[i][r];
      if (mp < 256) ws[OFF_FRE + ((size_t)mp * 256 + t) * 32 + cn] = v;
      else          ws[OFF_FIM + ((size_t)(mp - 256) * 256 + t) * 32 + cn] = v;
    }
  }
}

// uid in [0,1024): m = uid>>2, mt = (uid&3)*4 + wave
// B-panel (F[m] slice, 64 cp x 32 t) shared via double-buffered LDS (2x2560 shorts).
__device__ void phase_legfwd(float* ws, short* lds, int uid, int tid) {
  int m = uid >> 2, q = uid & 3;
  int lane = tid & 63;
  int cl = lane & 15, quad = lane >> 4;
  if (q * 64 + 63 < m) {   // whole block below diagonal -> zeros (uniform early-out, no barriers)
    int mt = q * 4 + (tid >> 6);
#pragma unroll
    for (int n = 0; n < 4; ++n) {
      int cp = n * 16 + cl;
      float* dst = ws + ((cp >= 32) ? OFF_SFIM : OFF_SFRE) + (size_t)m * 8192 + (cp & 31);
#pragma unroll
      for (int r = 0; r < 4; ++r) {
        int l = mt * 16 + quad * 4 + r;
        dst[(size_t)l * 32] = 0.f;
      }
    }
    return;
  }
  int mt = q * 4 + (tid >> 6);
  bool sk = (mt * 16 + 15) < m;
  const v8s* A = (const v8s*)(ws + OFF_PA) + (size_t)m * 8192;
  // coop-load mapping: half/c fixed per thread, tl = pass*4 + (tid>>6)
  int half = (tid >> 5) & 1, c = tid & 31, tb = tid >> 6;
  const float* srcb = ws + (half ? OFF_FIM : OFF_FRE) + (size_t)m * 8192 + c;
  short* myrow = lds;   // + buffer offset later
  int ldsw = (half * 32 + c) * 40 + tb;
  v4f acc[4];
#pragma unroll
  for (int n = 0; n < 4; ++n) acc[n] = (v4f){0.f, 0.f, 0.f, 0.f};
  v8s a_cur = A[(size_t)mt * 512 + lane];
  v8s a_nxt;
  {
    float pv[8];
#pragma unroll
    for (int pass = 0; pass < 8; ++pass)
      pv[pass] = srcb[(size_t)(pass * 4 + tb) * 32];
#pragma unroll
    for (int pass = 0; pass < 8; ++pass)
      myrow[ldsw + pass * 4] = f2bf(pv[pass]);
  }
  __syncthreads();
  for (int ks = 0; ks < 8; ++ks) {
    float pn[8];
    if (ks < 7) {
#pragma unroll
      for (int pass = 0; pass < 8; ++pass)
        pn[pass] = srcb[(size_t)((ks + 1) * 32 + pass * 4 + tb) * 32];
      a_nxt = A[(size_t)mt * 512 + (ks + 1) * 64 + lane];
    }
    const short* cur = lds + (ks & 1) * 2560;
    if (!sk) {
#pragma unroll
      for (int n = 0; n < 4; ++n) {
        v8s b = *(const v8s*)(cur + (n * 16 + cl) * 40 + quad * 8);
        acc[n] = __builtin_amdgcn_mfma_f32_16x16x32_bf16(a_cur, b, acc[n], 0, 0, 0);
      }
    }
    if (ks < 7) {
      short* nb = lds + ((ks + 1) & 1) * 2560;
#pragma unroll
      for (int pass = 0; pass < 8; ++pass)
        nb[ldsw + pass * 4] = f2bf(pn[pass]);
      a_cur = a_nxt;
      __syncthreads();
    }
  }
#pragma unroll
  for (int n = 0; n < 4; ++n) {
    int cp = n * 16 + cl;
    float* dst = ws + ((cp >= 32) ? OFF_SFIM : OFF_SFRE) + (size_t)m * 8192 + (cp & 31);
#pragma unroll
    for (int r = 0; r < 4; ++r) {
      int l = mt * 16 + quad * 4 + r;
      dst[(size_t)l * 32] = sk ? 0.f : acc[n][r];
    }
  }
}

// smem layout: wr 32x36 f | wi 32x36 f | fr 8x32 f | fi 8x32 f  (11264 B)
__device__ void phase_conv(const float* w_real, const float* w_imag, float* ws, char* smem,
                           int uid, int tid) {
  int l = uid >> 3, jq8 = uid & 7;
  int jl = tid >> 5, o = tid & 31;
  float* wr = (float*)smem;
  float* wi = wr + 32 * 36;
  float* fr = wi + 32 * 36;
  float* fi = fr + 8 * 32;
  {
    int oo = tid >> 3, i4 = (tid & 7) * 4;
    float tcr = ws[OFF_TC + l], tci = ws[OFF_TC + 128 + l];
#pragma unroll
    for (int q = 0; q < 4; ++q) {
      int i = i4 + q;
      float a = w_real[(size_t)l * 1024 + i * 32 + oo];
      float b = w_imag[(size_t)l * 1024 + i * 32 + oo];
      wr[oo * 36 + i] = tcr * a - tci * b;
      wi[oo * 36 + i] = tcr * b + tci * a;
    }
  }
  const float* SFRE = ws + OFF_SFRE;
  const float* SFIM = ws + OFF_SFIM;
  const float* WMW = ws + OFF_WMW;
  const int* WMI = (const int*)(ws + OFF_WMI);
  float wl[4]; int liv[4];
#pragma unroll
  for (int a = 0; a < 4; ++a) {
    wl[a] = ws[OFF_WLW + l * 4 + a];
    liv[a] = ((const int*)(ws + OFF_WLI))[l * 4 + a];
  }
  for (int ji = 0; ji < 4; ++ji) {
    int j = jq8 * 32 + ji * 8 + jl;
    int jp = (j < 255) ? j : 254;
    float accr = 0.f, acci = 0.f;
    for (int b = 0; b < 6; ++b) {
      float wm = WMW[jp * 6 + b];
      int jm = WMI[jp * 6 + b];
      bool mneg = (jm < 255);
      int mm = mneg ? (255 - jm) : (jm - 255);
      float fre_f = (mneg && (mm & 1)) ? -1.f : 1.f;
      float fim_f = mneg ? -fre_f : 1.f;
#pragma unroll
      for (int a = 0; a < 4; ++a) {
        float w = wm * wl[a];
        size_t base = ((size_t)mm * 256 + liv[a]) * 32 + o;
        accr = fmaf(w * fre_f, SFRE[base], accr);
        acci = fmaf(w * fim_f, SFIM[base], acci);
      }
    }
    __syncthreads();
    fr[jl * 32 + o] = accr;
    fi[jl * 32 + o] = acci;
    __syncthreads();
    float sr = 0.f, si = 0.f;
#pragma unroll
    for (int i0 = 0; i0 < 32; i0 += 4) {
      float4 f_r = *(const float4*)(fr + jl * 32 + i0);
      float4 f_i = *(const float4*)(fi + jl * 32 + i0);
      float4 w_r = *(const float4*)(wr + o * 36 + i0);
      float4 w_i = *(const float4*)(wi + o * 36 + i0);
      sr += f_r.x * w_r.x - f_i.x * w_i.x;  si += f_r.x * w_i.x + f_i.x * w_r.x;
      sr += f_r.y * w_r.y - f_i.y * w_i.y;  si += f_r.y * w_i.y + f_i.y * w_r.y;
      sr += f_r.z * w_r.z - f_i.z * w_i.z;  si += f_r.z * w_i.z + f_i.z * w_r.z;
      sr += f_r.w * w_r.w - f_i.w * w_i.w;  si += f_r.w * w_i.w + f_i.w * w_r.w;
    }
    if (j < 255) {
      float s = (j < 127 && ((127 - j) & 1)) ? -1.f : 1.f;   // (-1)^|m| for negative m
      ws[OFF_CRE + ((size_t)j * 128 + l) * 32 + o] = s * sr;
      ws[OFF_CIM + ((size_t)j * 128 + l) * 32 + o] = s * si;
    }
  }
}

// uid in [0,1020): j = uid>>2, mt = (uid&3)*4 + wave; A+B double-buffered (registers)
__device__ void phase_linv(float* ws, int uid, int tid) {
  int j = uid >> 2;
  int d = j - 127; int mm = (d < 0) ? -d : d;
  int mt = (uid & 3) * 4 + (tid >> 6), lane = tid & 63;
  const v8s* A = (const v8s*)(ws + OFF_PT) + (size_t)mm * 8192;
  int cl = lane & 15, lB = (lane >> 4) << 3;
  int quad = lane >> 4;
  v4f acc[4];
#pragma unroll
  for (int n = 0; n < 4; ++n) acc[n] = (v4f){0.f, 0.f, 0.f, 0.f};
  int ks0 = mm >> 5;
  const float* Cb[4];
#pragma unroll
  for (int n = 0; n < 4; ++n) {
    int cp = n * 16 + cl;
    Cb[n] = ws + (cp < 32 ? OFF_CRE : OFF_CIM) + ((size_t)j * 128 + lB) * 32 + (cp & 31);
  }
  float bv[4][8];
  v8s a_cur = A[(size_t)mt * 512 + ks0 * 64 + lane];
#pragma unroll
  for (int n = 0; n < 4; ++n)
#pragma unroll
    for (int j8 = 0; j8 < 8; ++j8) bv[n][j8] = Cb[n][(size_t)(ks0 * 32 + j8) * 32];
  for (int ks = ks0; ks < 4; ++ks) {   // l<128 only (padded flm zero above)
    float bn[4][8];
    v8s a_nxt;
    if (ks < 3) {
#pragma unroll
      for (int n = 0; n < 4; ++n)
#pragma unroll
        for (int j8 = 0; j8 < 8; ++j8) bn[n][j8] = Cb[n][(size_t)((ks + 1) * 32 + j8) * 32];
      a_nxt = A[(size_t)mt * 512 + (ks + 1) * 64 + lane];
    }
#pragma unroll
    for (int n = 0; n < 4; ++n) {
      v8s b;
#pragma unroll
      for (int j8 = 0; j8 < 8; ++j8) b[j8] = f2bf(bv[n][j8]);
      acc[n] = __builtin_amdgcn_mfma_f32_16x16x32_bf16(a_cur, b, acc[n], 0, 0, 0);
    }
    if (ks < 3) {
#pragma unroll
      for (int n = 0; n < 4; ++n)
#pragma unroll
        for (int j8 = 0; j8 < 8; ++j8) bv[n][j8] = bn[n][j8];
      a_cur = a_nxt;
    }
  }
#pragma unroll
  for (int n = 0; n < 4; ++n) {
    int cp = n * 16 + cl;
    float* dst = ws + ((cp >= 32) ? OFF_GIM : OFF_GRE) + (size_t)(cp & 31);
#pragma unroll
    for (int r = 0; r < 4; ++r) {
      int t = mt * 16 + quad * 4 + r;
      dst[((size_t)t * 255 + j) * 32] = acc[n][r];
    }
  }
}

// uid in [0,1024): nt = uid&1, mh = (uid>>1)&1, t = uid>>2
// B-panel shared via double-buffered LDS (2x640 shorts).
__device__ void phase_gemm_i(const float* ws, float* out, short* lds, int uid, int tid) {
  int nt = uid & 1, mh = (uid >> 1) & 1, t = uid >> 2;
  int wave = tid >> 6, lane = tid & 63;
  const v8s* A = (const v8s*)(ws + OFF_AI);
  const float* GRE = ws + OFF_GRE;
  const float* GIM = ws + OFF_GIM;
  int cl = lane & 15, quad = lane >> 4;
  int mtB = mh * 16 + wave * 4;
  int cn = nt * 16 + cl;
  int ck = tid >> 4, cc = tid & 15;
  int ccg = nt * 16 + cc;
  v4f acc[4];
#pragma unroll
  for (int i = 0; i < 4; ++i) acc[i] = (v4f){0.f, 0.f, 0.f, 0.f};
  v8s a_cur[4], a_nxt[4];
#pragma unroll
  for (int i = 0; i < 4; ++i) a_cur[i] = A[(size_t)((mtB + i) * 16 + 0) * 64 + lane];
  {
    float p0 = GRE[((size_t)t * 255 + ck) * 32 + ccg];          // k = ck < 255
    float p1 = GRE[((size_t)t * 255 + ck + 16) * 32 + ccg];     // k = ck+16 < 255
    lds[cc * 40 + ck] = f2bf(p0);
    lds[cc * 40 + ck + 16] = f2bf(p1);
  }
  __syncthreads();
  for (int ks = 0; ks < 16; ++ks) {
    float n0 = 0.f, n1 = 0.f;
    if (ks < 15) {
      int k0 = (ks + 1) * 32 + ck, k1 = k0 + 16;
      if (k0 < 255)      n0 = GRE[((size_t)t * 255 + k0) * 32 + ccg];
      else if (k0 < 510) n0 = GIM[((size_t)t * 255 + (k0 - 255)) * 32 + ccg];
      if (k1 < 255)      n1 = GRE[((size_t)t * 255 + k1) * 32 + ccg];
      else if (k1 < 510) n1 = GIM[((size_t)t * 255 + (k1 - 255)) * 32 + ccg];
#pragma unroll
      for (int i = 0; i < 4; ++i)
        a_nxt[i] = A[(size_t)((mtB + i) * 16 + ks + 1) * 64 + lane];
    }
    v8s b = *(const v8s*)(lds + (ks & 1) * 640 + cl * 40 + quad * 8);
#pragma unroll
    for (int i = 0; i < 4; ++i)
      acc[i] = __builtin_amdgcn_mfma_f32_16x16x32_bf16(a_cur[i], b, acc[i], 0, 0, 0);
    if (ks < 15) {
      short* nb = lds + ((ks + 1) & 1) * 640;
      nb[cc * 40 + ck] = f2bf(n0);
      nb[cc * 40 + ck + 16] = f2bf(n1);
#pragma unroll
      for (int i = 0; i < 4; ++i) a_cur[i] = a_nxt[i];
      __syncthreads();
    }
  }
#pragma unroll
  for (int i = 0; i < 4; ++i) {
    int mt = mtB + i;
#pragma unroll
    for (int r = 0; r < 4; ++r) {
      int phi = mt * 16 + quad * 4 + r;
      if (phi < 511) out[((size_t)t * 511 + phi) * 32 + cn] = acc[i][r];
    }
  }
}

// ================= kernels (plain launches only — NO cooperative launch; breaks graph capture, R10) =================
__global__ __launch_bounds__(256) void k_prepleg(const float* t_emb, const float* w_tr,
                                                 const float* b_tr, const float* w_ti,
                                                 const float* b_ti, float* ws) {
  // heavy legendre blocks FIRST (bid<256) so they start immediately; prep fills in after
  __shared__ __align__(16) char smem[32768];
  int bid = blockIdx.x;
  if (bid < 256) phase_legendre(ws, smem, bid, threadIdx.x);
  else phase_prep(t_emb, w_tr, b_tr, w_ti, b_ti, ws, bid - 256, threadIdx.x);
}
__global__ __launch_bounds__(256) void kw_gemm_f(const float* x, float* ws) {
  __shared__ __align__(16) short lds[2 * 640];
  phase_gemm_f(x, ws, lds, blockIdx.x, threadIdx.x);
}
__global__ __launch_bounds__(256) void kw_legfwd(float* ws) {
  __shared__ __align__(16) short lds[2 * 2560];
  phase_legfwd(ws, lds, blockIdx.x, threadIdx.x);
}
__global__ __launch_bounds__(256) void kw_conv(const float* w_real, const float* w_imag, float* ws) {
  __shared__ __align__(16) char smem[11264];
  phase_conv(w_real, w_imag, ws, smem, blockIdx.x, threadIdx.x);
}
__global__ __launch_bounds__(256) void kw_linv(float* ws) {
  phase_linv(ws, blockIdx.x, threadIdx.x);
}
__global__ __launch_bounds__(256) void kw_gemm_i(const float* ws, float* out) {
  __shared__ __align__(16) short lds[2 * 640];
  phase_gemm_i(ws, out, lds, blockIdx.x, threadIdx.x);
}

// ---------------- launch ----------------
extern "C" void kernel_launch(void* const* d_in, const int* in_sizes, int n_in,
                              void* d_out, int out_size, void* d_ws, size_t ws_size,
                              hipStream_t stream) {
  const float* x = (const float*)d_in[0];
  const float* t_emb = (const float*)d_in[1];
  const float* w_real = (const float*)d_in[2];
  const float* w_imag = (const float*)d_in[3];
  const float* w_tr = (const float*)d_in[4];
  const float* b_tr = (const float*)d_in[5];
  const float* w_ti = (const float*)d_in[6];
  const float* b_ti = (const float*)d_in[7];
  float* ws = (float*)d_ws;
  float* out = (float*)d_out;
  (void)in_sizes; (void)n_in; (void)out_size; (void)ws_size; // needs ~94 MB workspace

  hipLaunchKernelGGL(k_prepleg, dim3(2305), dim3(256), 0, stream,
                     t_emb, w_tr, b_tr, w_ti, b_ti, ws);
  hipLaunchKernelGGL(kw_gemm_f, dim3(1024), dim3(256), 0, stream, x, ws);
  hipLaunchKernelGGL(kw_legfwd, dim3(1024), dim3(256), 0, stream, ws);
  hipLaunchKernelGGL(kw_conv, dim3(1024), dim3(256), 0, stream, w_real, w_imag, ws);
  hipLaunchKernelGGL(kw_linv, dim3(1020), dim3(256), 0, stream, ws);
  hipLaunchKernelGGL(kw_gemm_i, dim3(1024), dim3(256), 0, stream, ws, out);
}